// Round 8
// baseline (1157.241 us; speedup 1.0000x reference)
//
#include <hip/hip_runtime.h>
#include <math.h>

// Problem constants (from reference)
#define Nn   100000
#define Ee   300000
#define FIN  128
#define Hdim 256
#define Ncls 40
#define Lnum 6
#define SCAN_B 98   // ceil(Nn/1024)
#define KP   264    // padded LDS row stride in shorts (528 B, 16B-aligned)
#define EMAX 768    // staged edge capacity per 64-row block (mean 192; fallback covers overflow)

typedef __attribute__((ext_vector_type(8))) short bf16x8;
typedef __attribute__((ext_vector_type(4))) float f32x4;

// ---------------- bf16 helpers (storage bf16, compute fp32) ----------------
__device__ __forceinline__ float bf2f(unsigned int u16) {
    unsigned int x = u16 << 16;
    return __builtin_bit_cast(float, x);
}
__device__ __forceinline__ unsigned short f2bf(float f) {
    unsigned int x = __builtin_bit_cast(unsigned int, f);
    x = (x + 0x7FFFu + ((x >> 16) & 1u)) >> 16;   // round-nearest-even
    return (unsigned short)x;
}
__device__ __forceinline__ void unpack2(unsigned int u, float& lo, float& hi) {
    lo = __builtin_bit_cast(float, u << 16);
    hi = __builtin_bit_cast(float, u & 0xFFFF0000u);
}
__device__ __forceinline__ unsigned int pack2(float a, float b) {
    return (unsigned int)f2bf(a) | ((unsigned int)f2bf(b) << 16);
}
__device__ __forceinline__ void acc8(float* a, float w, uint4 v) {
    float f0, f1;
    unpack2(v.x, f0, f1); a[0] += w * f0; a[1] += w * f1;
    unpack2(v.y, f0, f1); a[2] += w * f0; a[3] += w * f1;
    unpack2(v.z, f0, f1); a[4] += w * f0; a[5] += w * f1;
    unpack2(v.w, f0, f1); a[6] += w * f0; a[7] += w * f1;
}

// ---------------------------------------------------------------------------
// Graph preprocessing
// ---------------------------------------------------------------------------
__global__ void count_edges(const int* __restrict__ ei, int* __restrict__ cnt) {
    int e = blockIdx.x * blockDim.x + threadIdx.x;
    if (e < Ee) atomicAdd(&cnt[ei[Ee + e]], 1);   // row 1 of edge_index = dst
}

__global__ void scan_block(const int* __restrict__ cnt, int* __restrict__ iscan,
                           int* __restrict__ btot) {
    __shared__ int buf[1024];
    int t = threadIdx.x;
    int g = blockIdx.x * 1024 + t;
    int v = (g < Nn) ? cnt[g] : 0;
    buf[t] = v; __syncthreads();
    for (int off = 1; off < 1024; off <<= 1) {
        int x = buf[t];
        int a = (t >= off) ? buf[t - off] : 0;
        __syncthreads();
        buf[t] = x + a;
        __syncthreads();
    }
    if (g < Nn) iscan[g] = buf[t];
    if (t == 1023) btot[blockIdx.x] = buf[1023];
}

__global__ void scan_tops(const int* __restrict__ btot, int* __restrict__ bpref) {
    __shared__ int b[128];
    int t = threadIdx.x;
    int v = (t < SCAN_B) ? btot[t] : 0;
    b[t] = v; __syncthreads();
    for (int off = 1; off < 128; off <<= 1) {
        int x = b[t];
        int a = (t >= off) ? b[t - off] : 0;
        __syncthreads();
        b[t] = x + a;
        __syncthreads();
    }
    if (t < SCAN_B) bpref[t] = b[t] - v;   // exclusive
}

__global__ void scan_final(const int* __restrict__ cnt, const int* __restrict__ iscan,
                           const int* __restrict__ bpref, int* __restrict__ offs,
                           float* __restrict__ dinvp) {
    int g = blockIdx.x * 1024 + threadIdx.x;
    if (g < Nn) {
        int c = cnt[g];
        offs[g] = bpref[blockIdx.x] + iscan[g] - c;
        dinvp[g] = rsqrtf((float)(c + 1));    // deg = in-deg + self-loop
    }
    if (g == 0) offs[Nn] = Ee;
}

__global__ void fill_csr(const int* __restrict__ ei, const int* __restrict__ offs,
                         int* __restrict__ cur, const float* __restrict__ dinvp,
                         int* __restrict__ esrc, float* __restrict__ ew) {
    int e = blockIdx.x * blockDim.x + threadIdx.x;
    if (e >= Ee) return;
    int s = ei[e], d = ei[Ee + e];
    int p = offs[d] + atomicAdd(&cur[d], 1);
    esrc[p] = s;
    ew[p] = dinvp[s];
}

// ---------------------------------------------------------------------------
// All weight prep in ONE dispatch (blockIdx ranges).
// ---------------------------------------------------------------------------
__global__ void prep_weights(const float* __restrict__ conv_w, const float* __restrict__ w_in,
                             const float* __restrict__ out_w,
                             unsigned short* __restrict__ Whi,
                             unsigned short* __restrict__ Fhi,
                             unsigned short* __restrict__ Whd, unsigned short* __restrict__ Wld) {
    int b = blockIdx.x, t = threadIdx.x;
    if (b < 1536) {
        int id = b * 256 + t;                    // [0, 393216)
        int l = id >> 16, k = (id >> 8) & 255, n = id & 255;
        Whi[l * 65536 + n * 256 + k] = f2bf(conv_w[id]);
    } else if (b < 1664) {
        int id = (b - 1536) * 256 + t;           // [0, 32768)
        int k = id >> 8, n = id & 255;
        Fhi[n * FIN + k] = f2bf(w_in[id]);
    } else {
        int id = (b - 1664) * 256 + t;           // [0, 12288)
        int c = id >> 8, k = id & 255;
        float w = (c < Ncls) ? out_w[k * Ncls + c] : 0.f;
        unsigned short hi = f2bf(w);
        unsigned short lo = f2bf(w - bf2f(hi));
        Whd[c * 256 + k] = hi;
        Wld[c * 256 + k] = lo;
    }
}

// x fp32 -> bf16 (8 elems/thread)
__global__ void cvt_bf16(const float* __restrict__ src, unsigned short* __restrict__ dst, int n8) {
    int i = blockIdx.x * blockDim.x + threadIdx.x;
    if (i >= n8) return;
    float4 a = ((const float4*)src)[i * 2];
    float4 b = ((const float4*)src)[i * 2 + 1];
    uint4 o;
    o.x = pack2(a.x, a.y); o.y = pack2(a.z, a.w);
    o.z = pack2(b.x, b.y); o.w = pack2(b.z, b.w);
    ((uint4*)dst)[i] = o;
}

// ---------------------------------------------------------------------------
// BN-stats reduction: P[nb][512] partials -> bnsum/bnsq (32K spread atomics).
// Target arrays pre-zeroed once at startup.
// ---------------------------------------------------------------------------
__global__ void bn_reduce(const float* __restrict__ P, float* __restrict__ bnsum,
                          float* __restrict__ bnsq, int nb) {
    int c = threadIdx.x;                    // 0..255
    int per = (nb + gridDim.x - 1) / gridDim.x;
    int r0 = blockIdx.x * per;
    int r1 = r0 + per; if (r1 > nb) r1 = nb;
    float s = 0.f, q = 0.f;
    for (int r = r0; r < r1; ++r) {
        s += P[(size_t)r * 512 + c];
        q += P[(size_t)r * 512 + 256 + c];
    }
    if (r0 < r1) {
        atomicAdd(&bnsum[c], s);
        atomicAdd(&bnsq[c], q);
    }
}

// ---------------------------------------------------------------------------
// Plain MFMA GEMM (fc layer): C[M,256] = A[M,K] @ W^T + bias.
// ---------------------------------------------------------------------------
__global__ __launch_bounds__(512) void gemm_mfma(
    const unsigned short* __restrict__ A, unsigned short* __restrict__ C,
    const unsigned short* __restrict__ W,
    const float* __restrict__ bias, int K, int nrows)
{
    __shared__ __align__(16) unsigned short smem[18432];

    const int t    = threadIdx.x;
    const int lane = t & 63, wid = t >> 6;
    const int ln   = lane & 15, quad = lane >> 4;
    const int r64  = (wid >> 2) * 64, c64 = (wid & 3) * 64;
    const int r0   = blockIdx.x * 128;

    unsigned short* At = smem;
    unsigned short* Bt = smem + 5120;

    f32x4 acc[4][4];
#pragma unroll
    for (int i = 0; i < 4; ++i)
#pragma unroll
        for (int j = 0; j < 4; ++j) acc[i][j] = (f32x4){0.f, 0.f, 0.f, 0.f};

    const int arow = t >> 2, akq = t & 3;
    const bool arow_ok = (r0 + arow < nrows);
    const int nk = K >> 5;

    uint4 ga = make_uint4(0u, 0u, 0u, 0u);
    if (arow_ok) ga = *(const uint4*)&A[(size_t)(r0 + arow) * K + akq * 8];
    uint4 gb[2];
#pragma unroll
    for (int q = 0; q < 2; ++q) {
        int idx = t + 512 * q, row = idx >> 2, kq = idx & 3;
        gb[q] = *(const uint4*)&W[(size_t)row * K + kq * 8];
    }

    for (int kt = 0; kt < nk; ++kt) {
        __syncthreads();
        *(uint4*)&At[arow * 40 + akq * 8] = ga;
#pragma unroll
        for (int q = 0; q < 2; ++q) {
            int idx = t + 512 * q, row = idx >> 2, kq = idx & 3;
            *(uint4*)&Bt[row * 40 + kq * 8] = gb[q];
        }
        __syncthreads();
        if (kt + 1 < nk) {
            int k0 = (kt + 1) << 5;
            ga = make_uint4(0u, 0u, 0u, 0u);
            if (arow_ok) ga = *(const uint4*)&A[(size_t)(r0 + arow) * K + k0 + akq * 8];
#pragma unroll
            for (int q = 0; q < 2; ++q) {
                int idx = t + 512 * q, row = idx >> 2, kq = idx & 3;
                gb[q] = *(const uint4*)&W[(size_t)row * K + k0 + kq * 8];
            }
        }
        bf16x8 af[4], bf[4];
#pragma unroll
        for (int rt = 0; rt < 4; ++rt)
            af[rt] = *(const bf16x8*)&At[(r64 + rt * 16 + ln) * 40 + quad * 8];
#pragma unroll
        for (int ct = 0; ct < 4; ++ct)
            bf[ct] = *(const bf16x8*)&Bt[(c64 + ct * 16 + ln) * 40 + quad * 8];
#pragma unroll
        for (int rt = 0; rt < 4; ++rt)
#pragma unroll
            for (int ct = 0; ct < 4; ++ct)
                acc[rt][ct] = __builtin_amdgcn_mfma_f32_16x16x32_bf16(af[rt], bf[ct], acc[rt][ct], 0, 0, 0);
    }
    __syncthreads();

    float bc[4];
#pragma unroll
    for (int ct = 0; ct < 4; ++ct) bc[ct] = bias[c64 + ct * 16 + ln];

    // coalesced C store via wave-private pane
    unsigned short* Tt = &smem[wid * 2304];
    const int rr2 = lane & 31, jh = lane >> 5;
#pragma unroll
    for (int h = 0; h < 2; ++h) {
#pragma unroll
        for (int rr = 0; rr < 2; ++rr) {
            int rt = 2 * h + rr;
#pragma unroll
            for (int ct = 0; ct < 4; ++ct)
#pragma unroll
                for (int v = 0; v < 4; ++v)
                    Tt[(rr * 16 + quad * 4 + v) * 72 + ct * 16 + ln] = f2bf(acc[rt][ct][v] + bc[ct]);
        }
        __asm__ volatile("s_waitcnt lgkmcnt(0)" ::: "memory");
        int grow = r0 + r64 + h * 32 + rr2;
        if (grow < nrows) {
#pragma unroll
            for (int j = 0; j < 4; ++j) {
                uint4 v4 = *(const uint4*)&Tt[rr2 * 72 + jh * 32 + j * 8];
                *(uint4*)&C[(size_t)grow * 256 + c64 + jh * 32 + j * 8] = v4;
            }
        }
        __asm__ volatile("s_waitcnt lgkmcnt(0)" ::: "memory");
    }
}

// ---------------------------------------------------------------------------
// R8 (= R7 resubmit, v0..v3 zero-initialized): fused AGG + GEMM, 64-row tile.
//  - acc[2][4] = 32 AGPRs -> ~96 arch VGPRs free for the gather.
//  - QUAD-ROW gather: each half-wave owns exactly 4 rows, ALL in flight.
//  - 1563 blocks: finer tail granularity, better CU balance.
//  - edge staging in LDS, Pstats export, full-row coalesced store (validated).
// ---------------------------------------------------------------------------
__global__ __launch_bounds__(512, 4) void gemm_agg(
    const unsigned short* __restrict__ Hin,   // [Nn][256] prev activations
    unsigned short* __restrict__ C,           // T out [Nn][256]
    const unsigned short* __restrict__ W,     // [256][256], row = out col
    const float* __restrict__ bias,
    const int* __restrict__ offs, const int* __restrict__ esrc,
    const float* __restrict__ ew, const float* __restrict__ dinvp,
    float* __restrict__ bnsum, float* __restrict__ bnsq,
    float* __restrict__ Pstats)
{
    __shared__ __align__(16) unsigned short At[64 * KP];    // 33792 B
    __shared__ __align__(16) uint2 eL[EMAX];                //  6144 B
    __shared__ int oL[68];                                  //   272 B
    __shared__ float lsum[256], lsq[256];                   //  2048 B => ~42.3 KB

    const int t    = threadIdx.x;
    const int lane = t & 63, wid = t >> 6;
    const int ln   = lane & 15, quad = lane >> 4;
    const int wr32 = (wid >> 2) * 32, c64 = (wid & 3) * 64;
    const int r0   = blockIdx.x * 64;

    if (t < 256) { lsum[t] = 0.f; lsq[t] = 0.f; }

    // ---- stage offs + edge metadata (contiguous, coalesced) ----
    const int rEnd = (r0 + 64 <= Nn) ? (r0 + 64) : Nn;
    const int E0 = offs[r0];
    const int E1 = offs[rEnd];
    const int nE = E1 - E0;
    const bool staged = (nE <= EMAX);

    if (t < 65) {
        int idx = r0 + t; if (idx > Nn) idx = Nn;
        oL[t] = offs[idx];
    }
    if (staged) {
        for (int j = t; j < nE; j += 512)
            eL[j] = make_uint2((unsigned)esrc[E0 + j],
                               __builtin_bit_cast(unsigned, ew[E0 + j]));
    }
    __syncthreads();

    // ---- quad-row interleaved gather: half-wave hw owns rows [hw*4, hw*4+4) ----
    const int half = lane >> 5, l31 = lane & 31;
    const int rb = (wid * 2 + half) * 4;        // local row base, 0..60
    {
        float a0[8] = {0,0,0,0,0,0,0,0}, a1[8] = {0,0,0,0,0,0,0,0};
        float a2[8] = {0,0,0,0,0,0,0,0}, a3[8] = {0,0,0,0,0,0,0,0};
        const int n0 = r0 + rb, n1 = n0 + 1, n2 = n0 + 2, n3 = n0 + 3;
        int e0 = oL[rb],     f0 = oL[rb + 1];
        int e1 = oL[rb + 1], f1 = oL[rb + 2];
        int e2 = oL[rb + 2], f2 = oL[rb + 3];
        int e3 = oL[rb + 3], f3 = oL[rb + 4];
        float dn0 = 0.f, dn1 = 0.f, dn2 = 0.f, dn3 = 0.f;
        if (n0 < Nn) { dn0 = dinvp[n0];
            acc8(a0, dn0, *(const uint4*)&Hin[(size_t)n0 * Hdim + l31 * 8]); }
        if (n1 < Nn) { dn1 = dinvp[n1];
            acc8(a1, dn1, *(const uint4*)&Hin[(size_t)n1 * Hdim + l31 * 8]); }
        if (n2 < Nn) { dn2 = dinvp[n2];
            acc8(a2, dn2, *(const uint4*)&Hin[(size_t)n2 * Hdim + l31 * 8]); }
        if (n3 < Nn) { dn3 = dinvp[n3];
            acc8(a3, dn3, *(const uint4*)&Hin[(size_t)n3 * Hdim + l31 * 8]); }
        if (staged) {
            while ((e0 < f0) | (e1 < f1) | (e2 < f2) | (e3 < f3)) {
                bool d0 = e0 < f0, d1 = e1 < f1, d2 = e2 < f2, d3 = e3 < f3;
                uint4 v0 = make_uint4(0u,0u,0u,0u), v1 = v0, v2 = v0, v3 = v0;
                float w0 = 0.f, w1 = 0.f, w2 = 0.f, w3 = 0.f;
                if (d0) { uint2 s = eL[e0 - E0]; w0 = __builtin_bit_cast(float, s.y);
                          v0 = *(const uint4*)&Hin[(size_t)s.x * Hdim + l31 * 8]; }
                if (d1) { uint2 s = eL[e1 - E0]; w1 = __builtin_bit_cast(float, s.y);
                          v1 = *(const uint4*)&Hin[(size_t)s.x * Hdim + l31 * 8]; }
                if (d2) { uint2 s = eL[e2 - E0]; w2 = __builtin_bit_cast(float, s.y);
                          v2 = *(const uint4*)&Hin[(size_t)s.x * Hdim + l31 * 8]; }
                if (d3) { uint2 s = eL[e3 - E0]; w3 = __builtin_bit_cast(float, s.y);
                          v3 = *(const uint4*)&Hin[(size_t)s.x * Hdim + l31 * 8]; }
                if (d0) { acc8(a0, w0, v0); ++e0; }
                if (d1) { acc8(a1, w1, v1); ++e1; }
                if (d2) { acc8(a2, w2, v2); ++e2; }
                if (d3) { acc8(a3, w3, v3); ++e3; }
            }
        } else {
            for (int e = e0; e < f0; ++e) {
                acc8(a0, ew[e], *(const uint4*)&Hin[(size_t)esrc[e] * Hdim + l31 * 8]); }
            for (int e = e1; e < f1; ++e) {
                acc8(a1, ew[e], *(const uint4*)&Hin[(size_t)esrc[e] * Hdim + l31 * 8]); }
            for (int e = e2; e < f2; ++e) {
                acc8(a2, ew[e], *(const uint4*)&Hin[(size_t)esrc[e] * Hdim + l31 * 8]); }
            for (int e = e3; e < f3; ++e) {
                acc8(a3, ew[e], *(const uint4*)&Hin[(size_t)esrc[e] * Hdim + l31 * 8]); }
        }
#pragma unroll
        for (int k = 0; k < 8; ++k) {
            a0[k] *= dn0; a1[k] *= dn1; a2[k] *= dn2; a3[k] *= dn3;
        }
        *(uint4*)&At[(rb + 0) * KP + l31 * 8] =
            make_uint4(pack2(a0[0], a0[1]), pack2(a0[2], a0[3]),
                       pack2(a0[4], a0[5]), pack2(a0[6], a0[7]));
        *(uint4*)&At[(rb + 1) * KP + l31 * 8] =
            make_uint4(pack2(a1[0], a1[1]), pack2(a1[2], a1[3]),
                       pack2(a1[4], a1[5]), pack2(a1[6], a1[7]));
        *(uint4*)&At[(rb + 2) * KP + l31 * 8] =
            make_uint4(pack2(a2[0], a2[1]), pack2(a2[2], a2[3]),
                       pack2(a2[4], a2[5]), pack2(a2[6], a2[7]));
        *(uint4*)&At[(rb + 3) * KP + l31 * 8] =
            make_uint4(pack2(a3[0], a3[1]), pack2(a3[2], a3[3]),
                       pack2(a3[4], a3[5]), pack2(a3[6], a3[7]));
    }
    __syncthreads();   // At fully built

    // ---- barrier-free k-loop: A from LDS, B from global (L2-hot) ----
    f32x4 acc[2][4];
#pragma unroll
    for (int i = 0; i < 2; ++i)
#pragma unroll
        for (int j = 0; j < 4; ++j) acc[i][j] = (f32x4){0.f, 0.f, 0.f, 0.f};

#pragma unroll
    for (int kt = 0; kt < 8; ++kt) {
        bf16x8 af[2], bf[4];
#pragma unroll
        for (int ct = 0; ct < 4; ++ct)
            bf[ct] = *(const bf16x8*)&W[(size_t)(c64 + ct * 16 + ln) * 256 + kt * 32 + quad * 8];
#pragma unroll
        for (int rt = 0; rt < 2; ++rt)
            af[rt] = *(const bf16x8*)&At[(wr32 + rt * 16 + ln) * KP + kt * 32 + quad * 8];
#pragma unroll
        for (int rt = 0; rt < 2; ++rt)
#pragma unroll
            for (int ct = 0; ct < 4; ++ct)
                acc[rt][ct] = __builtin_amdgcn_mfma_f32_16x16x32_bf16(af[rt], bf[ct], acc[rt][ct], 0, 0, 0);
    }

    float bc[4];
#pragma unroll
    for (int ct = 0; ct < 4; ++ct) bc[ct] = bias[c64 + ct * 16 + ln];

    // ---- BN partial stats from acc (C/D layout: col=lane&15, row=quad*4+v) ----
#pragma unroll
    for (int ct = 0; ct < 4; ++ct) {
        float s = 0.f, qq = 0.f;
#pragma unroll
        for (int rt = 0; rt < 2; ++rt)
#pragma unroll
            for (int v = 0; v < 4; ++v) {
                int row = r0 + wr32 + rt * 16 + quad * 4 + v;
                if (row < Nn) {
                    float val = acc[rt][ct][v] + bc[ct];
                    s += val; qq += val * val;
                }
            }
        s  += __shfl_xor(s, 16);  s  += __shfl_xor(s, 32);
        qq += __shfl_xor(qq, 16); qq += __shfl_xor(qq, 32);
        if (quad == 0) { atomicAdd(&lsum[c64 + ct * 16 + ln], s); atomicAdd(&lsq[c64 + ct * 16 + ln], qq); }
    }

    __syncthreads();   // all k-loop LDS reads done; At reusable as pane

    // ---- transpose pane: acc -> At (bf16), then full-row coalesced store ----
#pragma unroll
    for (int rt = 0; rt < 2; ++rt)
#pragma unroll
        for (int ct = 0; ct < 4; ++ct)
#pragma unroll
            for (int v = 0; v < 4; ++v)
                At[(wr32 + rt * 16 + quad * 4 + v) * KP + c64 + ct * 16 + ln] =
                    f2bf(acc[rt][ct][v] + bc[ct]);
    __syncthreads();

    const int l31s = t & 31, rhalf = t >> 5;   // 16 rows per pass
#pragma unroll
    for (int p = 0; p < 4; ++p) {
        int lrow = p * 16 + rhalf;
        int grow = r0 + lrow;
        if (grow < Nn) {
            uint4 v4 = *(const uint4*)&At[lrow * KP + l31s * 8];
            *(uint4*)&C[(size_t)grow * 256 + l31s * 8] = v4;
        }
    }

    // ---- export stats: contention-free per-block stores (R3/R6-validated) ----
    if (t < 256) {
        if (Pstats) {
            Pstats[(size_t)blockIdx.x * 512 + t]       = lsum[t];
            Pstats[(size_t)blockIdx.x * 512 + 256 + t] = lsq[t];
        } else {
            atomicAdd(&bnsum[t], lsum[t]);   // fallback if ws too small
            atomicAdd(&bnsq[t], lsq[t]);
        }
    }
}

// ---------------------------------------------------------------------------
// Apply: H = relu(T*scale+shift) + 0.2*X (+ 0.7*H);  M (+)= w[l]*H
// ---------------------------------------------------------------------------
__global__ void apply_kernel(const unsigned short* __restrict__ T,
                             const unsigned short* __restrict__ X,
                             unsigned short* __restrict__ Hb, unsigned short* __restrict__ M,
                             const float* __restrict__ bnsum, const float* __restrict__ bnsq,
                             const float* __restrict__ gamma, const float* __restrict__ beta,
                             const float* __restrict__ res_w, int layer) {
    __shared__ float sc[256], sh[256];
    int t = threadIdx.x;   // blockDim = 256
    {
        float mean = bnsum[t] * (1.0f / Nn);
        float var  = fmaxf(bnsq[t] * (1.0f / Nn) - mean * mean, 0.f);
        float rstd = rsqrtf(var + 1e-5f);
        float s = gamma[t] * rstd;
        sc[t] = s; sh[t] = beta[t] - mean * s;
    }
    float m0 = res_w[0];
#pragma unroll
    for (int i = 1; i < Lnum; ++i) m0 = fmaxf(m0, res_w[i]);
    float se = 0.f, wl = 0.f;
#pragma unroll
    for (int i = 0; i < Lnum; ++i) {
        float e = __expf(res_w[i] - m0);
        se += e;
        if (i == layer) wl = e;
    }
    float wi = wl / se;
    __syncthreads();

    int idx = blockIdx.x * blockDim.x + t;
    int c8 = idx & 31;
    float scl[8], shl[8];
#pragma unroll
    for (int k = 0; k < 8; ++k) { scl[k] = sc[c8 * 8 + k]; shl[k] = sh[c8 * 8 + k]; }

    uint4 tv = ((const uint4*)T)[idx];
    uint4 xv = ((const uint4*)X)[idx];
    float tf[8], xf[8];
    unpack2(tv.x, tf[0], tf[1]); unpack2(tv.y, tf[2], tf[3]);
    unpack2(tv.z, tf[4], tf[5]); unpack2(tv.w, tf[6], tf[7]);
    unpack2(xv.x, xf[0], xf[1]); unpack2(xv.y, xf[2], xf[3]);
    unpack2(xv.z, xf[4], xf[5]); unpack2(xv.w, xf[6], xf[7]);

    float a[8];
#pragma unroll
    for (int k = 0; k < 8; ++k)
        a[k] = fmaxf(tf[k] * scl[k] + shl[k], 0.f) + 0.2f * xf[k];
    if (layer > 0) {
        uint4 hv = ((const uint4*)Hb)[idx];
        float hf[8];
        unpack2(hv.x, hf[0], hf[1]); unpack2(hv.y, hf[2], hf[3]);
        unpack2(hv.z, hf[4], hf[5]); unpack2(hv.w, hf[6], hf[7]);
#pragma unroll
        for (int k = 0; k < 8; ++k) a[k] += 0.7f * hf[k];
    }
    uint4 ho;
    ho.x = pack2(a[0], a[1]); ho.y = pack2(a[2], a[3]);
    ho.z = pack2(a[4], a[5]); ho.w = pack2(a[6], a[7]);
    ((uint4*)Hb)[idx] = ho;

    float m[8];
    if (layer == 0) {
#pragma unroll
        for (int k = 0; k < 8; ++k) m[k] = wi * a[k];
    } else {
        uint4 mv = ((const uint4*)M)[idx];
        float mf[8];
        unpack2(mv.x, mf[0], mf[1]); unpack2(mv.y, mf[2], mf[3]);
        unpack2(mv.z, mf[4], mf[5]); unpack2(mv.w, mf[6], mf[7]);
#pragma unroll
        for (int k = 0; k < 8; ++k) m[k] = mf[k] + wi * a[k];
    }
    uint4 mo;
    mo.x = pack2(m[0], m[1]); mo.y = pack2(m[2], m[3]);
    mo.z = pack2(m[4], m[5]); mo.w = pack2(m[6], m[7]);
    ((uint4*)M)[idx] = mo;
}

// ---------------------------------------------------------------------------
// Head via MFMA: logits[N,40] = M @ out_w + out_b, log_softmax rows.
// ---------------------------------------------------------------------------
__global__ __launch_bounds__(512) void head_mfma(const unsigned short* __restrict__ M,
                                                 const unsigned short* __restrict__ Whd,
                                                 const unsigned short* __restrict__ Wld,
                                                 const float* __restrict__ out_b,
                                                 float* __restrict__ out, int nrows) {
    __shared__ unsigned short At[128 * 40];   // 10 KB
    const int t    = threadIdx.x;
    const int lane = t & 63, wid = t >> 6;
    const int ln   = lane & 15, quad = lane >> 4;
    const int r0   = blockIdx.x * 128;

    f32x4 acc[3];
#pragma unroll
    for (int ct = 0; ct < 3; ++ct) acc[ct] = (f32x4){0.f, 0.f, 0.f, 0.f};

    for (int k0 = 0; k0 < 256; k0 += 32) {
        __syncthreads();
        {
            int row = t >> 2, kq = t & 3;
            uint4 g = make_uint4(0u, 0u, 0u, 0u);
            if (r0 + row < nrows)
                g = *(const uint4*)&M[(size_t)(r0 + row) * 256 + k0 + kq * 8];
            *(uint4*)&At[row * 40 + kq * 8] = g;
        }
        __syncthreads();
        bf16x8 af = *(const bf16x8*)&At[(wid * 16 + ln) * 40 + quad * 8];
#pragma unroll
        for (int ct = 0; ct < 3; ++ct) {
            int c = ct * 16 + ln;
            bf16x8 bh = *(const bf16x8*)&Whd[c * 256 + k0 + quad * 8];
            bf16x8 bl = *(const bf16x8*)&Wld[c * 256 + k0 + quad * 8];
            acc[ct] = __builtin_amdgcn_mfma_f32_16x16x32_bf16(af, bh, acc[ct], 0, 0, 0);
            acc[ct] = __builtin_amdgcn_mfma_f32_16x16x32_bf16(af, bl, acc[ct], 0, 0, 0);
        }
    }

    int   cc[3]; float bias[3];
#pragma unroll
    for (int ct = 0; ct < 3; ++ct) {
        cc[ct] = ct * 16 + ln;
        bias[ct] = (cc[ct] < Ncls) ? out_b[cc[ct]] : 0.f;
    }
#pragma unroll
    for (int v = 0; v < 4; ++v) {
        int row = r0 + wid * 16 + quad * 4 + v;
        float val[3];
#pragma unroll
        for (int ct = 0; ct < 3; ++ct) val[ct] = acc[ct][v] + bias[ct];
        float mx = -1e30f;
#pragma unroll
        for (int ct = 0; ct < 3; ++ct) if (cc[ct] < Ncls) mx = fmaxf(mx, val[ct]);
        mx = fmaxf(mx, __shfl_xor(mx, 1)); mx = fmaxf(mx, __shfl_xor(mx, 2));
        mx = fmaxf(mx, __shfl_xor(mx, 4)); mx = fmaxf(mx, __shfl_xor(mx, 8));
        float s = 0.f;
#pragma unroll
        for (int ct = 0; ct < 3; ++ct) if (cc[ct] < Ncls) s += __expf(val[ct] - mx);
        s += __shfl_xor(s, 1); s += __shfl_xor(s, 2);
        s += __shfl_xor(s, 4); s += __shfl_xor(s, 8);
        float lse = mx + __logf(s);
        if (row < nrows) {
            out[(size_t)row * Ncls + cc[0]] = val[0] - lse;
            out[(size_t)row * Ncls + cc[1]] = val[1] - lse;
            if (ln < 8) out[(size_t)row * Ncls + cc[2]] = val[2] - lse;
        }
    }
}

// ---------------------------------------------------------------------------
extern "C" void kernel_launch(void* const* d_in, const int* in_sizes, int n_in,
                              void* d_out, int out_size, void* d_ws, size_t ws_size,
                              hipStream_t stream)
{
    const float* x      = (const float*)d_in[0];
    const int*   ei     = (const int*)d_in[1];
    const float* w_in   = (const float*)d_in[2];
    const float* b_in   = (const float*)d_in[3];
    const float* conv_w = (const float*)d_in[4];
    const float* conv_b = (const float*)d_in[5];
    const float* gamma  = (const float*)d_in[6];
    const float* beta   = (const float*)d_in[7];
    const float* out_w  = (const float*)d_in[8];
    const float* out_b  = (const float*)d_in[9];
    const float* res_w  = (const float*)d_in[10];
    float* out = (float*)d_out;
    char* ws = (char*)d_ws;

    // workspace layout (~211 MB + 3.2 MB stats partials), 16B-aligned slots
    int*   cnt    = (int*)  (ws + 0);
    int*   cursor = (int*)  (ws + 400000);
    int*   offs   = (int*)  (ws + 800000);
    float* dinvp  = (float*)(ws + 1200016);
    int*   esrc   = (int*)  (ws + 1600016);
    float* ew     = (float*)(ws + 2800016);
    int*   iscan  = (int*)  (ws + 4002064);
    int*   btot   = (int*)  (ws + 4402064);
    int*   bpref  = (int*)  (ws + 4402576);
    unsigned short* Whi = (unsigned short*)(ws + 4403088);   // [L][256][256] bf16
    unsigned short* Fhi = (unsigned short*)(ws + 5975952);   // [256][128] bf16
    unsigned short* Whd = (unsigned short*)(ws + 6107024);   // [48][256] bf16
    unsigned short* Wld = (unsigned short*)(ws + 6131600);
    unsigned short* X   = (unsigned short*)(ws + 6156176);   // N*H bf16 = 51.2 MB each
    unsigned short* Hb  = X  + (size_t)Nn * Hdim;
    unsigned short* T   = Hb + (size_t)Nn * Hdim;
    unsigned short* M   = T  + (size_t)Nn * Hdim;
    unsigned short* xbf = M;   // scratch alias: fc input, dead before M first written

    // per-layer BN stats bnA[L][512] alias the head of the dead iscan region
    float* bnA = (float*)(ws + 4002064);

    const int gblocks = (Nn + 127) / 128;   // 782 (fc + head)
    const int ablocks = (Nn + 63) / 64;     // 1563 (fused agg+gemm)

    // BN-stats partials P[ablocks][512] past the fixed layout
    const size_t P_OFS = 6156176 + 4 * (size_t)Nn * Hdim * sizeof(unsigned short);
    const size_t P_BYTES = (size_t)ablocks * 512 * sizeof(float);
    float* Pst = (ws_size >= P_OFS + P_BYTES) ? (float*)(ws + P_OFS) : nullptr;

    hipMemsetAsync(cnt, 0, 800000, stream);  // cnt + cursor

    count_edges<<<(Ee + 255) / 256, 256, 0, stream>>>(ei, cnt);
    scan_block<<<SCAN_B, 1024, 0, stream>>>(cnt, iscan, btot);
    scan_tops<<<1, 128, 0, stream>>>(btot, bpref);
    scan_final<<<SCAN_B, 1024, 0, stream>>>(cnt, iscan, bpref, offs, dinvp);
    fill_csr<<<(Ee + 255) / 256, 256, 0, stream>>>(ei, offs, cursor, dinvp, esrc, ew);

    // iscan dead from here; zero the per-layer bn stats region once
    hipMemsetAsync(bnA, 0, Lnum * 512 * sizeof(float), stream);

    prep_weights<<<1712, 256, 0, stream>>>(conv_w, w_in, out_w,
                                           Whi, Fhi, Whd, Wld);
    cvt_bf16<<<(Nn * FIN / 8 + 255) / 256, 256, 0, stream>>>(x, xbf, Nn * FIN / 8);

    gemm_mfma<<<gblocks, 512, 0, stream>>>(xbf, X, Fhi, b_in, FIN, Nn);

    for (int i = 0; i < Lnum; ++i) {
        float* bnsumL = bnA + (size_t)i * 512;
        float* bnsqL  = bnsumL + 256;
        gemm_agg<<<ablocks, 512, 0, stream>>>(i == 0 ? X : Hb, T,
                                              Whi + (size_t)i * Hdim * Hdim,
                                              conv_b + (size_t)i * Hdim,
                                              offs, esrc, ew, dinvp,
                                              bnsumL, bnsqL, Pst);
        if (Pst)
            bn_reduce<<<64, 256, 0, stream>>>(Pst, bnsumL, bnsqL, ablocks);
        apply_kernel<<<(Nn * 32) / 256, 256, 0, stream>>>(T, X, Hb, M,
                                                          bnsumL, bnsqL,
                                                          gamma + (size_t)i * Hdim,
                                                          beta + (size_t)i * Hdim,
                                                          res_w, i);
    }

    head_mfma<<<gblocks, 512, 0, stream>>>(M, Whd, Wld, out_b, out, Nn);
}

// Round 9
// 1035.399 us; speedup vs baseline: 1.1177x; 1.1177x over previous
//
#include <hip/hip_runtime.h>
#include <math.h>

// Problem constants (from reference)
#define Nn   100000
#define Ee   300000
#define FIN  128
#define Hdim 256
#define Ncls 40
#define Lnum 6
#define SCAN_B 98   // ceil(Nn/1024)
#define KP   264    // padded LDS row stride in shorts (528 B, 16B-aligned)
#define EMAX 1152   // staged edge capacity per 128-row block (mean 384; fallback covers overflow)

typedef __attribute__((ext_vector_type(8))) short bf16x8;
typedef __attribute__((ext_vector_type(4))) float f32x4;

// ---------------- bf16 helpers (storage bf16, compute fp32) ----------------
__device__ __forceinline__ float bf2f(unsigned int u16) {
    unsigned int x = u16 << 16;
    return __builtin_bit_cast(float, x);
}
__device__ __forceinline__ unsigned short f2bf(float f) {
    unsigned int x = __builtin_bit_cast(unsigned int, f);
    x = (x + 0x7FFFu + ((x >> 16) & 1u)) >> 16;   // round-nearest-even
    return (unsigned short)x;
}
__device__ __forceinline__ void unpack2(unsigned int u, float& lo, float& hi) {
    lo = __builtin_bit_cast(float, u << 16);
    hi = __builtin_bit_cast(float, u & 0xFFFF0000u);
}
__device__ __forceinline__ unsigned int pack2(float a, float b) {
    return (unsigned int)f2bf(a) | ((unsigned int)f2bf(b) << 16);
}
__device__ __forceinline__ void acc8(float* a, float w, uint4 v) {
    float f0, f1;
    unpack2(v.x, f0, f1); a[0] += w * f0; a[1] += w * f1;
    unpack2(v.y, f0, f1); a[2] += w * f0; a[3] += w * f1;
    unpack2(v.z, f0, f1); a[4] += w * f0; a[5] += w * f1;
    unpack2(v.w, f0, f1); a[6] += w * f0; a[7] += w * f1;
}

// ---------------------------------------------------------------------------
// Graph preprocessing
// ---------------------------------------------------------------------------
__global__ void count_edges(const int* __restrict__ ei, int* __restrict__ cnt) {
    int e = blockIdx.x * blockDim.x + threadIdx.x;
    if (e < Ee) atomicAdd(&cnt[ei[Ee + e]], 1);   // row 1 of edge_index = dst
}

__global__ void scan_block(const int* __restrict__ cnt, int* __restrict__ iscan,
                           int* __restrict__ btot) {
    __shared__ int buf[1024];
    int t = threadIdx.x;
    int g = blockIdx.x * 1024 + t;
    int v = (g < Nn) ? cnt[g] : 0;
    buf[t] = v; __syncthreads();
    for (int off = 1; off < 1024; off <<= 1) {
        int x = buf[t];
        int a = (t >= off) ? buf[t - off] : 0;
        __syncthreads();
        buf[t] = x + a;
        __syncthreads();
    }
    if (g < Nn) iscan[g] = buf[t];
    if (t == 1023) btot[blockIdx.x] = buf[1023];
}

__global__ void scan_tops(const int* __restrict__ btot, int* __restrict__ bpref) {
    __shared__ int b[128];
    int t = threadIdx.x;
    int v = (t < SCAN_B) ? btot[t] : 0;
    b[t] = v; __syncthreads();
    for (int off = 1; off < 128; off <<= 1) {
        int x = b[t];
        int a = (t >= off) ? b[t - off] : 0;
        __syncthreads();
        b[t] = x + a;
        __syncthreads();
    }
    if (t < SCAN_B) bpref[t] = b[t] - v;   // exclusive
}

__global__ void scan_final(const int* __restrict__ cnt, const int* __restrict__ iscan,
                           const int* __restrict__ bpref, int* __restrict__ offs,
                           float* __restrict__ dinvp) {
    int g = blockIdx.x * 1024 + threadIdx.x;
    if (g < Nn) {
        int c = cnt[g];
        offs[g] = bpref[blockIdx.x] + iscan[g] - c;
        dinvp[g] = rsqrtf((float)(c + 1));    // deg = in-deg + self-loop
    }
    if (g == 0) offs[Nn] = Ee;
}

__global__ void fill_csr(const int* __restrict__ ei, const int* __restrict__ offs,
                         int* __restrict__ cur, const float* __restrict__ dinvp,
                         int* __restrict__ esrc, float* __restrict__ ew) {
    int e = blockIdx.x * blockDim.x + threadIdx.x;
    if (e >= Ee) return;
    int s = ei[e], d = ei[Ee + e];
    int p = offs[d] + atomicAdd(&cur[d], 1);
    esrc[p] = s;
    ew[p] = dinvp[s];
}

// ---------------------------------------------------------------------------
// All weight prep in ONE dispatch (blockIdx ranges).
// ---------------------------------------------------------------------------
__global__ void prep_weights(const float* __restrict__ conv_w, const float* __restrict__ w_in,
                             const float* __restrict__ out_w,
                             unsigned short* __restrict__ Whi,
                             unsigned short* __restrict__ Fhi,
                             unsigned short* __restrict__ Whd, unsigned short* __restrict__ Wld) {
    int b = blockIdx.x, t = threadIdx.x;
    if (b < 1536) {
        int id = b * 256 + t;                    // [0, 393216)
        int l = id >> 16, k = (id >> 8) & 255, n = id & 255;
        Whi[l * 65536 + n * 256 + k] = f2bf(conv_w[id]);
    } else if (b < 1664) {
        int id = (b - 1536) * 256 + t;           // [0, 32768)
        int k = id >> 8, n = id & 255;
        Fhi[n * FIN + k] = f2bf(w_in[id]);
    } else {
        int id = (b - 1664) * 256 + t;           // [0, 12288)
        int c = id >> 8, k = id & 255;
        float w = (c < Ncls) ? out_w[k * Ncls + c] : 0.f;
        unsigned short hi = f2bf(w);
        unsigned short lo = f2bf(w - bf2f(hi));
        Whd[c * 256 + k] = hi;
        Wld[c * 256 + k] = lo;
    }
}

// x fp32 -> bf16 (8 elems/thread)
__global__ void cvt_bf16(const float* __restrict__ src, unsigned short* __restrict__ dst, int n8) {
    int i = blockIdx.x * blockDim.x + threadIdx.x;
    if (i >= n8) return;
    float4 a = ((const float4*)src)[i * 2];
    float4 b = ((const float4*)src)[i * 2 + 1];
    uint4 o;
    o.x = pack2(a.x, a.y); o.y = pack2(a.z, a.w);
    o.z = pack2(b.x, b.y); o.w = pack2(b.z, b.w);
    ((uint4*)dst)[i] = o;
}

// ---------------------------------------------------------------------------
// BN-stats reduction: P[nb][512] partials -> bnsum/bnsq (32K spread atomics).
// Target arrays pre-zeroed once at startup.
// ---------------------------------------------------------------------------
__global__ void bn_reduce(const float* __restrict__ P, float* __restrict__ bnsum,
                          float* __restrict__ bnsq, int nb) {
    int c = threadIdx.x;                    // 0..255
    int per = (nb + gridDim.x - 1) / gridDim.x;
    int r0 = blockIdx.x * per;
    int r1 = r0 + per; if (r1 > nb) r1 = nb;
    float s = 0.f, q = 0.f;
    for (int r = r0; r < r1; ++r) {
        s += P[(size_t)r * 512 + c];
        q += P[(size_t)r * 512 + 256 + c];
    }
    if (r0 < r1) {
        atomicAdd(&bnsum[c], s);
        atomicAdd(&bnsq[c], q);
    }
}

// ---------------------------------------------------------------------------
// Plain MFMA GEMM (fc layer): C[M,256] = A[M,K] @ W^T + bias.
// ---------------------------------------------------------------------------
__global__ __launch_bounds__(512) void gemm_mfma(
    const unsigned short* __restrict__ A, unsigned short* __restrict__ C,
    const unsigned short* __restrict__ W,
    const float* __restrict__ bias, int K, int nrows)
{
    __shared__ __align__(16) unsigned short smem[18432];

    const int t    = threadIdx.x;
    const int lane = t & 63, wid = t >> 6;
    const int ln   = lane & 15, quad = lane >> 4;
    const int r64  = (wid >> 2) * 64, c64 = (wid & 3) * 64;
    const int r0   = blockIdx.x * 128;

    unsigned short* At = smem;
    unsigned short* Bt = smem + 5120;

    f32x4 acc[4][4];
#pragma unroll
    for (int i = 0; i < 4; ++i)
#pragma unroll
        for (int j = 0; j < 4; ++j) acc[i][j] = (f32x4){0.f, 0.f, 0.f, 0.f};

    const int arow = t >> 2, akq = t & 3;
    const bool arow_ok = (r0 + arow < nrows);
    const int nk = K >> 5;

    uint4 ga = make_uint4(0u, 0u, 0u, 0u);
    if (arow_ok) ga = *(const uint4*)&A[(size_t)(r0 + arow) * K + akq * 8];
    uint4 gb[2];
#pragma unroll
    for (int q = 0; q < 2; ++q) {
        int idx = t + 512 * q, row = idx >> 2, kq = idx & 3;
        gb[q] = *(const uint4*)&W[(size_t)row * K + kq * 8];
    }

    for (int kt = 0; kt < nk; ++kt) {
        __syncthreads();
        *(uint4*)&At[arow * 40 + akq * 8] = ga;
#pragma unroll
        for (int q = 0; q < 2; ++q) {
            int idx = t + 512 * q, row = idx >> 2, kq = idx & 3;
            *(uint4*)&Bt[row * 40 + kq * 8] = gb[q];
        }
        __syncthreads();
        if (kt + 1 < nk) {
            int k0 = (kt + 1) << 5;
            ga = make_uint4(0u, 0u, 0u, 0u);
            if (arow_ok) ga = *(const uint4*)&A[(size_t)(r0 + arow) * K + k0 + akq * 8];
#pragma unroll
            for (int q = 0; q < 2; ++q) {
                int idx = t + 512 * q, row = idx >> 2, kq = idx & 3;
                gb[q] = *(const uint4*)&W[(size_t)row * K + k0 + kq * 8];
            }
        }
        bf16x8 af[4], bf[4];
#pragma unroll
        for (int rt = 0; rt < 4; ++rt)
            af[rt] = *(const bf16x8*)&At[(r64 + rt * 16 + ln) * 40 + quad * 8];
#pragma unroll
        for (int ct = 0; ct < 4; ++ct)
            bf[ct] = *(const bf16x8*)&Bt[(c64 + ct * 16 + ln) * 40 + quad * 8];
#pragma unroll
        for (int rt = 0; rt < 4; ++rt)
#pragma unroll
            for (int ct = 0; ct < 4; ++ct)
                acc[rt][ct] = __builtin_amdgcn_mfma_f32_16x16x32_bf16(af[rt], bf[ct], acc[rt][ct], 0, 0, 0);
    }
    __syncthreads();

    float bc[4];
#pragma unroll
    for (int ct = 0; ct < 4; ++ct) bc[ct] = bias[c64 + ct * 16 + ln];

    // coalesced C store via wave-private pane
    unsigned short* Tt = &smem[wid * 2304];
    const int rr2 = lane & 31, jh = lane >> 5;
#pragma unroll
    for (int h = 0; h < 2; ++h) {
#pragma unroll
        for (int rr = 0; rr < 2; ++rr) {
            int rt = 2 * h + rr;
#pragma unroll
            for (int ct = 0; ct < 4; ++ct)
#pragma unroll
                for (int v = 0; v < 4; ++v)
                    Tt[(rr * 16 + quad * 4 + v) * 72 + ct * 16 + ln] = f2bf(acc[rt][ct][v] + bc[ct]);
        }
        __asm__ volatile("s_waitcnt lgkmcnt(0)" ::: "memory");
        int grow = r0 + r64 + h * 32 + rr2;
        if (grow < nrows) {
#pragma unroll
            for (int j = 0; j < 4; ++j) {
                uint4 v4 = *(const uint4*)&Tt[rr2 * 72 + jh * 32 + j * 8];
                *(uint4*)&C[(size_t)grow * 256 + c64 + jh * 32 + j * 8] = v4;
            }
        }
        __asm__ volatile("s_waitcnt lgkmcnt(0)" ::: "memory");
    }
}

// ---------------------------------------------------------------------------
// R9: R6-validated fused AGG + GEMM (128-row tile, dual-row gather) with a
// 2-DEEP software pipeline re-added on top of the dual-row interleave:
// 4 independent global loads in flight per half-wave (2 rows x 2 deep).
// R8's 64-row quad-row tile regressed (2x W L2 traffic + 2x per-block
// overhead + 4-chain lgkm serialization) - reverted.
// Stats exported as per-block Pstats stores (R3/R6-validated).
// ---------------------------------------------------------------------------
__global__ __launch_bounds__(512, 4) void gemm_agg(
    const unsigned short* __restrict__ Hin,   // [Nn][256] prev activations
    unsigned short* __restrict__ C,           // T out [Nn][256]
    const unsigned short* __restrict__ W,     // [256][256], row = out col
    const float* __restrict__ bias,
    const int* __restrict__ offs, const int* __restrict__ esrc,
    const float* __restrict__ ew, const float* __restrict__ dinvp,
    float* __restrict__ bnsum, float* __restrict__ bnsq,
    float* __restrict__ Pstats)
{
    __shared__ __align__(16) unsigned short At[128 * KP];   // 67584 B
    __shared__ __align__(16) uint2 eL[EMAX];                //  9216 B
    __shared__ int oL[132];                                 //   528 B
    __shared__ float lsum[256], lsq[256];                   //  2048 B => ~79.4 KB

    const int t    = threadIdx.x;
    const int lane = t & 63, wid = t >> 6;
    const int ln   = lane & 15, quad = lane >> 4;
    const int r64  = (wid >> 2) * 64, c64 = (wid & 3) * 64;
    const int r0   = blockIdx.x * 128;

    if (t < 256) { lsum[t] = 0.f; lsq[t] = 0.f; }

    // ---- stage offs + edge metadata (contiguous, coalesced) ----
    const int rEnd = (r0 + 128 <= Nn) ? (r0 + 128) : Nn;
    const int E0 = offs[r0];
    const int E1 = offs[rEnd];
    const int nE = E1 - E0;
    const bool staged = (nE <= EMAX);

    if (t < 129) {
        int idx = r0 + t; if (idx > Nn) idx = Nn;
        oL[t] = offs[idx];
    }
    if (staged) {
        for (int j = t; j < nE; j += 512)
            eL[j] = make_uint2((unsigned)esrc[E0 + j],
                               __builtin_bit_cast(unsigned, ew[E0 + j]));
    }
    __syncthreads();

    // ---- dual-row gather with 2-deep edge pipeline ----
    const int half = lane >> 5, l31 = lane & 31;
#pragma unroll 1
    for (int p = 0; p < 4; ++p) {
        const int rA = (wid * 2 + half) * 8 + 2 * p, rB = rA + 1;
        const int nA = r0 + rA, nB = r0 + rB;
        float a[8] = {0.f,0.f,0.f,0.f,0.f,0.f,0.f,0.f};
        float b[8] = {0.f,0.f,0.f,0.f,0.f,0.f,0.f,0.f};
        int eA = oL[rA], eA1 = oL[rA + 1];
        int eB = oL[rB], eB1 = oL[rB + 1];
        float dnA = 0.f, dnB = 0.f;
        if (nA < Nn) {
            dnA = dinvp[nA];
            acc8(a, dnA, *(const uint4*)&Hin[(size_t)nA * Hdim + l31 * 8]);
        }
        if (nB < Nn) {
            dnB = dinvp[nB];
            acc8(b, dnB, *(const uint4*)&Hin[(size_t)nB * Hdim + l31 * 8]);
        }
        if (staged) {
            // prologue: load first edge of each row
            bool dA = eA < eA1, dB = eB < eB1;
            uint4 vA = make_uint4(0u,0u,0u,0u), vB = vA;
            float wA = 0.f, wB = 0.f;
            if (dA) { uint2 s = eL[eA - E0]; wA = __builtin_bit_cast(float, s.y);
                      vA = *(const uint4*)&Hin[(size_t)s.x * Hdim + l31 * 8]; }
            if (dB) { uint2 s = eL[eB - E0]; wB = __builtin_bit_cast(float, s.y);
                      vB = *(const uint4*)&Hin[(size_t)s.x * Hdim + l31 * 8]; }
            while (dA | dB) {
                // issue next edge's loads BEFORE consuming current (2-deep)
                bool dA2 = dA && (eA + 1 < eA1), dB2 = dB && (eB + 1 < eB1);
                uint4 vA2 = make_uint4(0u,0u,0u,0u), vB2 = vA2;
                float wA2 = 0.f, wB2 = 0.f;
                if (dA2) { uint2 s = eL[eA + 1 - E0]; wA2 = __builtin_bit_cast(float, s.y);
                           vA2 = *(const uint4*)&Hin[(size_t)s.x * Hdim + l31 * 8]; }
                if (dB2) { uint2 s = eL[eB + 1 - E0]; wB2 = __builtin_bit_cast(float, s.y);
                           vB2 = *(const uint4*)&Hin[(size_t)s.x * Hdim + l31 * 8]; }
                if (dA) { acc8(a, wA, vA); ++eA; }
                if (dB) { acc8(b, wB, vB); ++eB; }
                vA = vA2; wA = wA2; dA = dA2;
                vB = vB2; wB = wB2; dB = dB2;
            }
        } else {
            for (int e = eA; e < eA1; ++e) {
                int s = esrc[e]; float w = ew[e];
                acc8(a, w, *(const uint4*)&Hin[(size_t)s * Hdim + l31 * 8]);
            }
            for (int e = eB; e < eB1; ++e) {
                int s = esrc[e]; float w = ew[e];
                acc8(b, w, *(const uint4*)&Hin[(size_t)s * Hdim + l31 * 8]);
            }
        }
#pragma unroll
        for (int k = 0; k < 8; ++k) { a[k] *= dnA; b[k] *= dnB; }
        *(uint4*)&At[rA * KP + l31 * 8] =
            make_uint4(pack2(a[0], a[1]), pack2(a[2], a[3]),
                       pack2(a[4], a[5]), pack2(a[6], a[7]));
        *(uint4*)&At[rB * KP + l31 * 8] =
            make_uint4(pack2(b[0], b[1]), pack2(b[2], b[3]),
                       pack2(b[4], b[5]), pack2(b[6], b[7]));
    }
    __syncthreads();   // At fully built

    // ---- barrier-free k-loop: A from LDS, B from global (L2-hot) ----
    f32x4 acc[4][4];
#pragma unroll
    for (int i = 0; i < 4; ++i)
#pragma unroll
        for (int j = 0; j < 4; ++j) acc[i][j] = (f32x4){0.f, 0.f, 0.f, 0.f};

#pragma unroll
    for (int kt = 0; kt < 8; ++kt) {
        bf16x8 af[4], bf[4];
#pragma unroll
        for (int ct = 0; ct < 4; ++ct)
            bf[ct] = *(const bf16x8*)&W[(size_t)(c64 + ct * 16 + ln) * 256 + kt * 32 + quad * 8];
#pragma unroll
        for (int rt = 0; rt < 4; ++rt)
            af[rt] = *(const bf16x8*)&At[(r64 + rt * 16 + ln) * KP + kt * 32 + quad * 8];
#pragma unroll
        for (int rt = 0; rt < 4; ++rt)
#pragma unroll
            for (int ct = 0; ct < 4; ++ct)
                acc[rt][ct] = __builtin_amdgcn_mfma_f32_16x16x32_bf16(af[rt], bf[ct], acc[rt][ct], 0, 0, 0);
    }

    float bc[4];
#pragma unroll
    for (int ct = 0; ct < 4; ++ct) bc[ct] = bias[c64 + ct * 16 + ln];

    // ---- BN partial stats from acc (C/D layout: col=lane&15, row=quad*4+v) ----
#pragma unroll
    for (int ct = 0; ct < 4; ++ct) {
        float s = 0.f, qq = 0.f;
#pragma unroll
        for (int rt = 0; rt < 4; ++rt)
#pragma unroll
            for (int v = 0; v < 4; ++v) {
                int row = r0 + r64 + rt * 16 + quad * 4 + v;
                if (row < Nn) {
                    float val = acc[rt][ct][v] + bc[ct];
                    s += val; qq += val * val;
                }
            }
        s  += __shfl_xor(s, 16);  s  += __shfl_xor(s, 32);
        qq += __shfl_xor(qq, 16); qq += __shfl_xor(qq, 32);
        if (quad == 0) { atomicAdd(&lsum[c64 + ct * 16 + ln], s); atomicAdd(&lsq[c64 + ct * 16 + ln], qq); }
    }

    __syncthreads();   // all k-loop LDS reads done; At reusable as pane

    // ---- transpose pane: acc -> At (bf16), then full-row coalesced store ----
#pragma unroll
    for (int rt = 0; rt < 4; ++rt)
#pragma unroll
        for (int ct = 0; ct < 4; ++ct)
#pragma unroll
            for (int v = 0; v < 4; ++v)
                At[(r64 + rt * 16 + quad * 4 + v) * KP + c64 + ct * 16 + ln] =
                    f2bf(acc[rt][ct][v] + bc[ct]);
    __syncthreads();

    const int l31s = t & 31, rhalf = t >> 5;   // 16 rows per pass
#pragma unroll
    for (int p = 0; p < 8; ++p) {
        int lrow = p * 16 + rhalf;
        int grow = r0 + lrow;
        if (grow < Nn) {
            uint4 v4 = *(const uint4*)&At[lrow * KP + l31s * 8];
            *(uint4*)&C[(size_t)grow * 256 + l31s * 8] = v4;
        }
    }

    // ---- export stats: contention-free per-block stores (R3/R6-validated) ----
    if (t < 256) {
        if (Pstats) {
            Pstats[(size_t)blockIdx.x * 512 + t]       = lsum[t];
            Pstats[(size_t)blockIdx.x * 512 + 256 + t] = lsq[t];
        } else {
            atomicAdd(&bnsum[t], lsum[t]);   // fallback if ws too small
            atomicAdd(&bnsq[t], lsq[t]);
        }
    }
}

// ---------------------------------------------------------------------------
// Apply: H = relu(T*scale+shift) + 0.2*X (+ 0.7*H);  M (+)= w[l]*H
// ---------------------------------------------------------------------------
__global__ void apply_kernel(const unsigned short* __restrict__ T,
                             const unsigned short* __restrict__ X,
                             unsigned short* __restrict__ Hb, unsigned short* __restrict__ M,
                             const float* __restrict__ bnsum, const float* __restrict__ bnsq,
                             const float* __restrict__ gamma, const float* __restrict__ beta,
                             const float* __restrict__ res_w, int layer) {
    __shared__ float sc[256], sh[256];
    int t = threadIdx.x;   // blockDim = 256
    {
        float mean = bnsum[t] * (1.0f / Nn);
        float var  = fmaxf(bnsq[t] * (1.0f / Nn) - mean * mean, 0.f);
        float rstd = rsqrtf(var + 1e-5f);
        float s = gamma[t] * rstd;
        sc[t] = s; sh[t] = beta[t] - mean * s;
    }
    float m0 = res_w[0];
#pragma unroll
    for (int i = 1; i < Lnum; ++i) m0 = fmaxf(m0, res_w[i]);
    float se = 0.f, wl = 0.f;
#pragma unroll
    for (int i = 0; i < Lnum; ++i) {
        float e = __expf(res_w[i] - m0);
        se += e;
        if (i == layer) wl = e;
    }
    float wi = wl / se;
    __syncthreads();

    int idx = blockIdx.x * blockDim.x + t;
    int c8 = idx & 31;
    float scl[8], shl[8];
#pragma unroll
    for (int k = 0; k < 8; ++k) { scl[k] = sc[c8 * 8 + k]; shl[k] = sh[c8 * 8 + k]; }

    uint4 tv = ((const uint4*)T)[idx];
    uint4 xv = ((const uint4*)X)[idx];
    float tf[8], xf[8];
    unpack2(tv.x, tf[0], tf[1]); unpack2(tv.y, tf[2], tf[3]);
    unpack2(tv.z, tf[4], tf[5]); unpack2(tv.w, tf[6], tf[7]);
    unpack2(xv.x, xf[0], xf[1]); unpack2(xv.y, xf[2], xf[3]);
    unpack2(xv.z, xf[4], xf[5]); unpack2(xv.w, xf[6], xf[7]);

    float a[8];
#pragma unroll
    for (int k = 0; k < 8; ++k)
        a[k] = fmaxf(tf[k] * scl[k] + shl[k], 0.f) + 0.2f * xf[k];
    if (layer > 0) {
        uint4 hv = ((const uint4*)Hb)[idx];
        float hf[8];
        unpack2(hv.x, hf[0], hf[1]); unpack2(hv.y, hf[2], hf[3]);
        unpack2(hv.z, hf[4], hf[5]); unpack2(hv.w, hf[6], hf[7]);
#pragma unroll
        for (int k = 0; k < 8; ++k) a[k] += 0.7f * hf[k];
    }
    uint4 ho;
    ho.x = pack2(a[0], a[1]); ho.y = pack2(a[2], a[3]);
    ho.z = pack2(a[4], a[5]); ho.w = pack2(a[6], a[7]);
    ((uint4*)Hb)[idx] = ho;

    float m[8];
    if (layer == 0) {
#pragma unroll
        for (int k = 0; k < 8; ++k) m[k] = wi * a[k];
    } else {
        uint4 mv = ((const uint4*)M)[idx];
        float mf[8];
        unpack2(mv.x, mf[0], mf[1]); unpack2(mv.y, mf[2], mf[3]);
        unpack2(mv.z, mf[4], mf[5]); unpack2(mv.w, mf[6], mf[7]);
#pragma unroll
        for (int k = 0; k < 8; ++k) m[k] = mf[k] + wi * a[k];
    }
    uint4 mo;
    mo.x = pack2(m[0], m[1]); mo.y = pack2(m[2], m[3]);
    mo.z = pack2(m[4], m[5]); mo.w = pack2(m[6], m[7]);
    ((uint4*)M)[idx] = mo;
}

// ---------------------------------------------------------------------------
// Head via MFMA: logits[N,40] = M @ out_w + out_b, log_softmax rows.
// ---------------------------------------------------------------------------
__global__ __launch_bounds__(512) void head_mfma(const unsigned short* __restrict__ M,
                                                 const unsigned short* __restrict__ Whd,
                                                 const unsigned short* __restrict__ Wld,
                                                 const float* __restrict__ out_b,
                                                 float* __restrict__ out, int nrows) {
    __shared__ unsigned short At[128 * 40];   // 10 KB
    const int t    = threadIdx.x;
    const int lane = t & 63, wid = t >> 6;
    const int ln   = lane & 15, quad = lane >> 4;
    const int r0   = blockIdx.x * 128;

    f32x4 acc[3];
#pragma unroll
    for (int ct = 0; ct < 3; ++ct) acc[ct] = (f32x4){0.f, 0.f, 0.f, 0.f};

    for (int k0 = 0; k0 < 256; k0 += 32) {
        __syncthreads();
        {
            int row = t >> 2, kq = t & 3;
            uint4 g = make_uint4(0u, 0u, 0u, 0u);
            if (r0 + row < nrows)
                g = *(const uint4*)&M[(size_t)(r0 + row) * 256 + k0 + kq * 8];
            *(uint4*)&At[row * 40 + kq * 8] = g;
        }
        __syncthreads();
        bf16x8 af = *(const bf16x8*)&At[(wid * 16 + ln) * 40 + quad * 8];
#pragma unroll
        for (int ct = 0; ct < 3; ++ct) {
            int c = ct * 16 + ln;
            bf16x8 bh = *(const bf16x8*)&Whd[c * 256 + k0 + quad * 8];
            bf16x8 bl = *(const bf16x8*)&Wld[c * 256 + k0 + quad * 8];
            acc[ct] = __builtin_amdgcn_mfma_f32_16x16x32_bf16(af, bh, acc[ct], 0, 0, 0);
            acc[ct] = __builtin_amdgcn_mfma_f32_16x16x32_bf16(af, bl, acc[ct], 0, 0, 0);
        }
    }

    int   cc[3]; float bias[3];
#pragma unroll
    for (int ct = 0; ct < 3; ++ct) {
        cc[ct] = ct * 16 + ln;
        bias[ct] = (cc[ct] < Ncls) ? out_b[cc[ct]] : 0.f;
    }
#pragma unroll
    for (int v = 0; v < 4; ++v) {
        int row = r0 + wid * 16 + quad * 4 + v;
        float val[3];
#pragma unroll
        for (int ct = 0; ct < 3; ++ct) val[ct] = acc[ct][v] + bias[ct];
        float mx = -1e30f;
#pragma unroll
        for (int ct = 0; ct < 3; ++ct) if (cc[ct] < Ncls) mx = fmaxf(mx, val[ct]);
        mx = fmaxf(mx, __shfl_xor(mx, 1)); mx = fmaxf(mx, __shfl_xor(mx, 2));
        mx = fmaxf(mx, __shfl_xor(mx, 4)); mx = fmaxf(mx, __shfl_xor(mx, 8));
        float s = 0.f;
#pragma unroll
        for (int ct = 0; ct < 3; ++ct) if (cc[ct] < Ncls) s += __expf(val[ct] - mx);
        s += __shfl_xor(s, 1); s += __shfl_xor(s, 2);
        s += __shfl_xor(s, 4); s += __shfl_xor(s, 8);
        float lse = mx + __logf(s);
        if (row < nrows) {
            out[(size_t)row * Ncls + cc[0]] = val[0] - lse;
            out[(size_t)row * Ncls + cc[1]] = val[1] - lse;
            if (ln < 8) out[(size_t)row * Ncls + cc[2]] = val[2] - lse;
        }
    }
}

// ---------------------------------------------------------------------------
extern "C" void kernel_launch(void* const* d_in, const int* in_sizes, int n_in,
                              void* d_out, int out_size, void* d_ws, size_t ws_size,
                              hipStream_t stream)
{
    const float* x      = (const float*)d_in[0];
    const int*   ei     = (const int*)d_in[1];
    const float* w_in   = (const float*)d_in[2];
    const float* b_in   = (const float*)d_in[3];
    const float* conv_w = (const float*)d_in[4];
    const float* conv_b = (const float*)d_in[5];
    const float* gamma  = (const float*)d_in[6];
    const float* beta   = (const float*)d_in[7];
    const float* out_w  = (const float*)d_in[8];
    const float* out_b  = (const float*)d_in[9];
    const float* res_w  = (const float*)d_in[10];
    float* out = (float*)d_out;
    char* ws = (char*)d_ws;

    // workspace layout (~211 MB + 1.6 MB stats partials), 16B-aligned slots
    int*   cnt    = (int*)  (ws + 0);
    int*   cursor = (int*)  (ws + 400000);
    int*   offs   = (int*)  (ws + 800000);
    float* dinvp  = (float*)(ws + 1200016);
    int*   esrc   = (int*)  (ws + 1600016);
    float* ew     = (float*)(ws + 2800016);
    int*   iscan  = (int*)  (ws + 4002064);
    int*   btot   = (int*)  (ws + 4402064);
    int*   bpref  = (int*)  (ws + 4402576);
    unsigned short* Whi = (unsigned short*)(ws + 4403088);   // [L][256][256] bf16
    unsigned short* Fhi = (unsigned short*)(ws + 5975952);   // [256][128] bf16
    unsigned short* Whd = (unsigned short*)(ws + 6107024);   // [48][256] bf16
    unsigned short* Wld = (unsigned short*)(ws + 6131600);
    unsigned short* X   = (unsigned short*)(ws + 6156176);   // N*H bf16 = 51.2 MB each
    unsigned short* Hb  = X  + (size_t)Nn * Hdim;
    unsigned short* T   = Hb + (size_t)Nn * Hdim;
    unsigned short* M   = T  + (size_t)Nn * Hdim;
    unsigned short* xbf = M;   // scratch alias: fc input, dead before M first written

    // per-layer BN stats bnA[L][512] alias the head of the dead iscan region
    float* bnA = (float*)(ws + 4002064);

    const int gblocks = (Nn + 127) / 128;   // 782

    // BN-stats partials P[gblocks][512] past the fixed layout (R3-validated fit)
    const size_t P_OFS = 6156176 + 4 * (size_t)Nn * Hdim * sizeof(unsigned short);
    const size_t P_BYTES = (size_t)gblocks * 512 * sizeof(float);
    float* Pst = (ws_size >= P_OFS + P_BYTES) ? (float*)(ws + P_OFS) : nullptr;

    hipMemsetAsync(cnt, 0, 800000, stream);  // cnt + cursor

    count_edges<<<(Ee + 255) / 256, 256, 0, stream>>>(ei, cnt);
    scan_block<<<SCAN_B, 1024, 0, stream>>>(cnt, iscan, btot);
    scan_tops<<<1, 128, 0, stream>>>(btot, bpref);
    scan_final<<<SCAN_B, 1024, 0, stream>>>(cnt, iscan, bpref, offs, dinvp);
    fill_csr<<<(Ee + 255) / 256, 256, 0, stream>>>(ei, offs, cursor, dinvp, esrc, ew);

    // iscan dead from here; zero the per-layer bn stats region once
    hipMemsetAsync(bnA, 0, Lnum * 512 * sizeof(float), stream);

    prep_weights<<<1712, 256, 0, stream>>>(conv_w, w_in, out_w,
                                           Whi, Fhi, Whd, Wld);
    cvt_bf16<<<(Nn * FIN / 8 + 255) / 256, 256, 0, stream>>>(x, xbf, Nn * FIN / 8);

    gemm_mfma<<<gblocks, 512, 0, stream>>>(xbf, X, Fhi, b_in, FIN, Nn);

    for (int i = 0; i < Lnum; ++i) {
        float* bnsumL = bnA + (size_t)i * 512;
        float* bnsqL  = bnsumL + 256;
        gemm_agg<<<gblocks, 512, 0, stream>>>(i == 0 ? X : Hb, T,
                                              Whi + (size_t)i * Hdim * Hdim,
                                              conv_b + (size_t)i * Hdim,
                                              offs, esrc, ew, dinvp,
                                              bnsumL, bnsqL, Pst);
        if (Pst)
            bn_reduce<<<64, 256, 0, stream>>>(Pst, bnsumL, bnsqL, gblocks);
        apply_kernel<<<(Nn * 32) / 256, 256, 0, stream>>>(T, X, Hb, M,
                                                          bnsumL, bnsqL,
                                                          gamma + (size_t)i * Hdim,
                                                          beta + (size_t)i * Hdim,
                                                          res_w, i);
    }

    head_mfma<<<gblocks, 512, 0, stream>>>(M, Whd, Wld, out_b, out, Nn);
}

// Round 11
// 1026.377 us; speedup vs baseline: 1.1275x; 1.0088x over previous
//
#include <hip/hip_runtime.h>
#include <math.h>

// Problem constants (from reference)
#define Nn   100000
#define Ee   300000
#define FIN  128
#define Hdim 256
#define Ncls 40
#define Lnum 6
#define SCAN_B 98   // ceil(Nn/1024)
#define KP   264    // padded LDS row stride in shorts (528 B, 16B-aligned)
#define EMAX 1152   // staged edge capacity per 128-row block (mean 384; fallback covers overflow)

typedef __attribute__((ext_vector_type(8))) short bf16x8;
typedef __attribute__((ext_vector_type(4))) float f32x4;

// ---------------- bf16 helpers (storage bf16, compute fp32) ----------------
__device__ __forceinline__ float bf2f(unsigned int u16) {
    unsigned int x = u16 << 16;
    return __builtin_bit_cast(float, x);
}
__device__ __forceinline__ unsigned short f2bf(float f) {
    unsigned int x = __builtin_bit_cast(unsigned int, f);
    x = (x + 0x7FFFu + ((x >> 16) & 1u)) >> 16;   // round-nearest-even
    return (unsigned short)x;
}
__device__ __forceinline__ void unpack2(unsigned int u, float& lo, float& hi) {
    lo = __builtin_bit_cast(float, u << 16);
    hi = __builtin_bit_cast(float, u & 0xFFFF0000u);
}
__device__ __forceinline__ unsigned int pack2(float a, float b) {
    return (unsigned int)f2bf(a) | ((unsigned int)f2bf(b) << 16);
}
__device__ __forceinline__ void acc8(float* a, float w, uint4 v) {
    float f0, f1;
    unpack2(v.x, f0, f1); a[0] += w * f0; a[1] += w * f1;
    unpack2(v.y, f0, f1); a[2] += w * f0; a[3] += w * f1;
    unpack2(v.z, f0, f1); a[4] += w * f0; a[5] += w * f1;
    unpack2(v.w, f0, f1); a[6] += w * f0; a[7] += w * f1;
}

// ---------------------------------------------------------------------------
// Graph preprocessing
// ---------------------------------------------------------------------------
__global__ void count_edges(const int* __restrict__ ei, int* __restrict__ cnt) {
    int e = blockIdx.x * blockDim.x + threadIdx.x;
    if (e < Ee) atomicAdd(&cnt[ei[Ee + e]], 1);   // row 1 of edge_index = dst
}

__global__ void scan_block(const int* __restrict__ cnt, int* __restrict__ iscan,
                           int* __restrict__ btot) {
    __shared__ int buf[1024];
    int t = threadIdx.x;
    int g = blockIdx.x * 1024 + t;
    int v = (g < Nn) ? cnt[g] : 0;
    buf[t] = v; __syncthreads();
    for (int off = 1; off < 1024; off <<= 1) {
        int x = buf[t];
        int a = (t >= off) ? buf[t - off] : 0;
        __syncthreads();
        buf[t] = x + a;
        __syncthreads();
    }
    if (g < Nn) iscan[g] = buf[t];
    if (t == 1023) btot[blockIdx.x] = buf[1023];
}

__global__ void scan_tops(const int* __restrict__ btot, int* __restrict__ bpref) {
    __shared__ int b[128];
    int t = threadIdx.x;
    int v = (t < SCAN_B) ? btot[t] : 0;
    b[t] = v; __syncthreads();
    for (int off = 1; off < 128; off <<= 1) {
        int x = b[t];
        int a = (t >= off) ? b[t - off] : 0;
        __syncthreads();
        b[t] = x + a;
        __syncthreads();
    }
    if (t < SCAN_B) bpref[t] = b[t] - v;   // exclusive
}

__global__ void scan_final(const int* __restrict__ cnt, const int* __restrict__ iscan,
                           const int* __restrict__ bpref, int* __restrict__ offs,
                           float* __restrict__ dinvp) {
    int g = blockIdx.x * 1024 + threadIdx.x;
    if (g < Nn) {
        int c = cnt[g];
        offs[g] = bpref[blockIdx.x] + iscan[g] - c;
        dinvp[g] = rsqrtf((float)(c + 1));    // deg = in-deg + self-loop
    }
    if (g == 0) offs[Nn] = Ee;
}

__global__ void fill_csr(const int* __restrict__ ei, const int* __restrict__ offs,
                         int* __restrict__ cur, const float* __restrict__ dinvp,
                         int* __restrict__ esrc, float* __restrict__ ew) {
    int e = blockIdx.x * blockDim.x + threadIdx.x;
    if (e >= Ee) return;
    int s = ei[e], d = ei[Ee + e];
    int p = offs[d] + atomicAdd(&cur[d], 1);
    esrc[p] = s;
    ew[p] = dinvp[s];
}

// ---------------------------------------------------------------------------
// All weight prep in ONE dispatch (blockIdx ranges).
// ---------------------------------------------------------------------------
__global__ void prep_weights(const float* __restrict__ conv_w, const float* __restrict__ w_in,
                             const float* __restrict__ out_w,
                             unsigned short* __restrict__ Whi,
                             unsigned short* __restrict__ Fhi,
                             unsigned short* __restrict__ Whd, unsigned short* __restrict__ Wld) {
    int b = blockIdx.x, t = threadIdx.x;
    if (b < 1536) {
        int id = b * 256 + t;                    // [0, 393216)
        int l = id >> 16, k = (id >> 8) & 255, n = id & 255;
        Whi[l * 65536 + n * 256 + k] = f2bf(conv_w[id]);
    } else if (b < 1664) {
        int id = (b - 1536) * 256 + t;           // [0, 32768)
        int k = id >> 8, n = id & 255;
        Fhi[n * FIN + k] = f2bf(w_in[id]);
    } else {
        int id = (b - 1664) * 256 + t;           // [0, 12288)
        int c = id >> 8, k = id & 255;
        float w = (c < Ncls) ? out_w[k * Ncls + c] : 0.f;
        unsigned short hi = f2bf(w);
        unsigned short lo = f2bf(w - bf2f(hi));
        Whd[c * 256 + k] = hi;
        Wld[c * 256 + k] = lo;
    }
}

// x fp32 -> bf16 (8 elems/thread)
__global__ void cvt_bf16(const float* __restrict__ src, unsigned short* __restrict__ dst, int n8) {
    int i = blockIdx.x * blockDim.x + threadIdx.x;
    if (i >= n8) return;
    float4 a = ((const float4*)src)[i * 2];
    float4 b = ((const float4*)src)[i * 2 + 1];
    uint4 o;
    o.x = pack2(a.x, a.y); o.y = pack2(a.z, a.w);
    o.z = pack2(b.x, b.y); o.w = pack2(b.z, b.w);
    ((uint4*)dst)[i] = o;
}

// ---------------------------------------------------------------------------
// BN-stats reduction: P[nb][512] partials -> bnsum/bnsq (32K spread atomics).
// ---------------------------------------------------------------------------
__global__ void bn_reduce(const float* __restrict__ P, float* __restrict__ bnsum,
                          float* __restrict__ bnsq, int nb) {
    int c = threadIdx.x;                    // 0..255
    int per = (nb + gridDim.x - 1) / gridDim.x;
    int r0 = blockIdx.x * per;
    int r1 = r0 + per; if (r1 > nb) r1 = nb;
    float s = 0.f, q = 0.f;
    for (int r = r0; r < r1; ++r) {
        s += P[(size_t)r * 512 + c];
        q += P[(size_t)r * 512 + 256 + c];
    }
    if (r0 < r1) {
        atomicAdd(&bnsum[c], s);
        atomicAdd(&bnsq[c], q);
    }
}

// ---------------------------------------------------------------------------
// R11: fc GEMM, barrier-free style. R10 BUG FIXED: a 128-short row is
// 16 uint4 (not 8) -> stage 2048 uint4 (4/thread), row=idx>>4, kq=idx&15.
// Stage uses 17408 of the 18432-short smem union; MFMA max read 17400.
// ---------------------------------------------------------------------------
__global__ __launch_bounds__(512) void gemm_fc(
    const unsigned short* __restrict__ A,    // [Nn][128] bf16
    unsigned short* __restrict__ C,          // [Nn][256] bf16 out
    const unsigned short* __restrict__ W,    // Fhi [256][128], row = out col
    const float* __restrict__ bias, int nrows)
{
    __shared__ __align__(16) unsigned short smem[18432];   // stage 17408 / pane 18432 union (shorts)

    const int t    = threadIdx.x;
    const int lane = t & 63, wid = t >> 6;
    const int ln   = lane & 15, quad = lane >> 4;
    const int r64  = (wid >> 2) * 64, c64 = (wid & 3) * 64;
    const int r0   = blockIdx.x * 128;

    // stage A: 128 rows x 16 uint4 = 2048 uint4, 4/thread, coalesced
#pragma unroll
    for (int q = 0; q < 4; ++q) {
        int idx = t + 512 * q;               // 0..2047
        int row = idx >> 4, kq = idx & 15;   // 16 uint4 per 128-short row
        uint4 g = make_uint4(0u, 0u, 0u, 0u);
        if (r0 + row < nrows)
            g = *(const uint4*)&A[(size_t)(r0 + row) * FIN + kq * 8];
        *(uint4*)&smem[row * 136 + kq * 8] = g;
    }
    __syncthreads();

    f32x4 acc[4][4];
#pragma unroll
    for (int i = 0; i < 4; ++i)
#pragma unroll
        for (int j = 0; j < 4; ++j) acc[i][j] = (f32x4){0.f, 0.f, 0.f, 0.f};

#pragma unroll
    for (int kt = 0; kt < 4; ++kt) {
        bf16x8 af[4], bf[4];
#pragma unroll
        for (int ct = 0; ct < 4; ++ct)
            bf[ct] = *(const bf16x8*)&W[(size_t)(c64 + ct * 16 + ln) * FIN + kt * 32 + quad * 8];
#pragma unroll
        for (int rt = 0; rt < 4; ++rt)
            af[rt] = *(const bf16x8*)&smem[(r64 + rt * 16 + ln) * 136 + kt * 32 + quad * 8];
#pragma unroll
        for (int rt = 0; rt < 4; ++rt)
#pragma unroll
            for (int ct = 0; ct < 4; ++ct)
                acc[rt][ct] = __builtin_amdgcn_mfma_f32_16x16x32_bf16(af[rt], bf[ct], acc[rt][ct], 0, 0, 0);
    }
    __syncthreads();   // stage region free

    float bc[4];
#pragma unroll
    for (int ct = 0; ct < 4; ++ct) bc[ct] = bias[c64 + ct * 16 + ln];

    // coalesced C store via wave-private pane (validated structure)
    unsigned short* Tt = &smem[wid * 2304];
    const int rr2 = lane & 31, jh = lane >> 5;
#pragma unroll
    for (int h = 0; h < 2; ++h) {
#pragma unroll
        for (int rr = 0; rr < 2; ++rr) {
            int rt = 2 * h + rr;
#pragma unroll
            for (int ct = 0; ct < 4; ++ct)
#pragma unroll
                for (int v = 0; v < 4; ++v)
                    Tt[(rr * 16 + quad * 4 + v) * 72 + ct * 16 + ln] = f2bf(acc[rt][ct][v] + bc[ct]);
        }
        __asm__ volatile("s_waitcnt lgkmcnt(0)" ::: "memory");
        int grow = r0 + r64 + h * 32 + rr2;
        if (grow < nrows) {
#pragma unroll
            for (int j = 0; j < 4; ++j) {
                uint4 v4 = *(const uint4*)&Tt[rr2 * 72 + jh * 32 + j * 8];
                *(uint4*)&C[(size_t)grow * 256 + c64 + jh * 32 + j * 8] = v4;
            }
        }
        __asm__ volatile("s_waitcnt lgkmcnt(0)" ::: "memory");
    }
}

// ---------------------------------------------------------------------------
// Fused AGG + GEMM (R6/R9-validated, UNCHANGED): 128-row tile, dual-row
// gather with LDS-staged edges, barrier-free k-loop, Pstats export.
// ---------------------------------------------------------------------------
__global__ __launch_bounds__(512, 4) void gemm_agg(
    const unsigned short* __restrict__ Hin,   // [Nn][256] prev activations
    unsigned short* __restrict__ C,           // T out [Nn][256]
    const unsigned short* __restrict__ W,     // [256][256], row = out col
    const float* __restrict__ bias,
    const int* __restrict__ offs, const int* __restrict__ esrc,
    const float* __restrict__ ew, const float* __restrict__ dinvp,
    float* __restrict__ bnsum, float* __restrict__ bnsq,
    float* __restrict__ Pstats)
{
    __shared__ __align__(16) unsigned short At[128 * KP];   // 67584 B
    __shared__ __align__(16) uint2 eL[EMAX];                //  9216 B
    __shared__ int oL[132];                                 //   528 B
    __shared__ float lsum[256], lsq[256];                   //  2048 B => ~79.4 KB

    const int t    = threadIdx.x;
    const int lane = t & 63, wid = t >> 6;
    const int ln   = lane & 15, quad = lane >> 4;
    const int r64  = (wid >> 2) * 64, c64 = (wid & 3) * 64;
    const int r0   = blockIdx.x * 128;

    if (t < 256) { lsum[t] = 0.f; lsq[t] = 0.f; }

    const int rEnd = (r0 + 128 <= Nn) ? (r0 + 128) : Nn;
    const int E0 = offs[r0];
    const int E1 = offs[rEnd];
    const int nE = E1 - E0;
    const bool staged = (nE <= EMAX);

    if (t < 129) {
        int idx = r0 + t; if (idx > Nn) idx = Nn;
        oL[t] = offs[idx];
    }
    if (staged) {
        for (int j = t; j < nE; j += 512)
            eL[j] = make_uint2((unsigned)esrc[E0 + j],
                               __builtin_bit_cast(unsigned, ew[E0 + j]));
    }
    __syncthreads();

    // dual-row gather (compiler pipelines across iterations)
    const int half = lane >> 5, l31 = lane & 31;
#pragma unroll 1
    for (int p = 0; p < 4; ++p) {
        const int rA = (wid * 2 + half) * 8 + 2 * p, rB = rA + 1;
        const int nA = r0 + rA, nB = r0 + rB;
        float a[8] = {0.f,0.f,0.f,0.f,0.f,0.f,0.f,0.f};
        float b[8] = {0.f,0.f,0.f,0.f,0.f,0.f,0.f,0.f};
        int eA = oL[rA], eA1 = oL[rA + 1];
        int eB = oL[rB], eB1 = oL[rB + 1];
        float dnA = 0.f, dnB = 0.f;
        if (nA < Nn) {
            dnA = dinvp[nA];
            acc8(a, dnA, *(const uint4*)&Hin[(size_t)nA * Hdim + l31 * 8]);
        }
        if (nB < Nn) {
            dnB = dinvp[nB];
            acc8(b, dnB, *(const uint4*)&Hin[(size_t)nB * Hdim + l31 * 8]);
        }
        if (staged) {
            while ((eA < eA1) | (eB < eB1)) {
                bool dA = eA < eA1, dB = eB < eB1;
                uint4 vA = make_uint4(0u,0u,0u,0u), vB = vA;
                float wA = 0.f, wB = 0.f;
                if (dA) { uint2 s = eL[eA - E0]; wA = __builtin_bit_cast(float, s.y);
                          vA = *(const uint4*)&Hin[(size_t)s.x * Hdim + l31 * 8]; }
                if (dB) { uint2 s = eL[eB - E0]; wB = __builtin_bit_cast(float, s.y);
                          vB = *(const uint4*)&Hin[(size_t)s.x * Hdim + l31 * 8]; }
                if (dA) { acc8(a, wA, vA); ++eA; }
                if (dB) { acc8(b, wB, vB); ++eB; }
            }
        } else {
            for (int e = eA; e < eA1; ++e) {
                int s = esrc[e]; float w = ew[e];
                acc8(a, w, *(const uint4*)&Hin[(size_t)s * Hdim + l31 * 8]);
            }
            for (int e = eB; e < eB1; ++e) {
                int s = esrc[e]; float w = ew[e];
                acc8(b, w, *(const uint4*)&Hin[(size_t)s * Hdim + l31 * 8]);
            }
        }
#pragma unroll
        for (int k = 0; k < 8; ++k) { a[k] *= dnA; b[k] *= dnB; }
        *(uint4*)&At[rA * KP + l31 * 8] =
            make_uint4(pack2(a[0], a[1]), pack2(a[2], a[3]),
                       pack2(a[4], a[5]), pack2(a[6], a[7]));
        *(uint4*)&At[rB * KP + l31 * 8] =
            make_uint4(pack2(b[0], b[1]), pack2(b[2], b[3]),
                       pack2(b[4], b[5]), pack2(b[6], b[7]));
    }
    __syncthreads();   // At fully built

    f32x4 acc[4][4];
#pragma unroll
    for (int i = 0; i < 4; ++i)
#pragma unroll
        for (int j = 0; j < 4; ++j) acc[i][j] = (f32x4){0.f, 0.f, 0.f, 0.f};

#pragma unroll
    for (int kt = 0; kt < 8; ++kt) {
        bf16x8 af[4], bf[4];
#pragma unroll
        for (int ct = 0; ct < 4; ++ct)
            bf[ct] = *(const bf16x8*)&W[(size_t)(c64 + ct * 16 + ln) * 256 + kt * 32 + quad * 8];
#pragma unroll
        for (int rt = 0; rt < 4; ++rt)
            af[rt] = *(const bf16x8*)&At[(r64 + rt * 16 + ln) * KP + kt * 32 + quad * 8];
#pragma unroll
        for (int rt = 0; rt < 4; ++rt)
#pragma unroll
            for (int ct = 0; ct < 4; ++ct)
                acc[rt][ct] = __builtin_amdgcn_mfma_f32_16x16x32_bf16(af[rt], bf[ct], acc[rt][ct], 0, 0, 0);
    }

    float bc[4];
#pragma unroll
    for (int ct = 0; ct < 4; ++ct) bc[ct] = bias[c64 + ct * 16 + ln];

#pragma unroll
    for (int ct = 0; ct < 4; ++ct) {
        float s = 0.f, qq = 0.f;
#pragma unroll
        for (int rt = 0; rt < 4; ++rt)
#pragma unroll
            for (int v = 0; v < 4; ++v) {
                int row = r0 + r64 + rt * 16 + quad * 4 + v;
                if (row < Nn) {
                    float val = acc[rt][ct][v] + bc[ct];
                    s += val; qq += val * val;
                }
            }
        s  += __shfl_xor(s, 16);  s  += __shfl_xor(s, 32);
        qq += __shfl_xor(qq, 16); qq += __shfl_xor(qq, 32);
        if (quad == 0) { atomicAdd(&lsum[c64 + ct * 16 + ln], s); atomicAdd(&lsq[c64 + ct * 16 + ln], qq); }
    }

    __syncthreads();

#pragma unroll
    for (int rt = 0; rt < 4; ++rt)
#pragma unroll
        for (int ct = 0; ct < 4; ++ct)
#pragma unroll
            for (int v = 0; v < 4; ++v)
                At[(r64 + rt * 16 + quad * 4 + v) * KP + c64 + ct * 16 + ln] =
                    f2bf(acc[rt][ct][v] + bc[ct]);
    __syncthreads();

    const int l31s = t & 31, rhalf = t >> 5;
#pragma unroll
    for (int p = 0; p < 8; ++p) {
        int lrow = p * 16 + rhalf;
        int grow = r0 + lrow;
        if (grow < Nn) {
            uint4 v4 = *(const uint4*)&At[lrow * KP + l31s * 8];
            *(uint4*)&C[(size_t)grow * 256 + l31s * 8] = v4;
        }
    }

    if (t < 256) {
        if (Pstats) {
            Pstats[(size_t)blockIdx.x * 512 + t]       = lsum[t];
            Pstats[(size_t)blockIdx.x * 512 + 256 + t] = lsq[t];
        } else {
            atomicAdd(&bnsum[t], lsum[t]);
            atomicAdd(&bnsq[t], lsq[t]);
        }
    }
}

// ---------------------------------------------------------------------------
// Apply (fallback / M path): H = relu(T*s+b) + 0.2X (+0.7Hprev); M (+)= w*H
// ---------------------------------------------------------------------------
__global__ void apply_kernel(const unsigned short* __restrict__ T,
                             const unsigned short* __restrict__ X,
                             unsigned short* __restrict__ Hb, unsigned short* __restrict__ M,
                             const float* __restrict__ bnsum, const float* __restrict__ bnsq,
                             const float* __restrict__ gamma, const float* __restrict__ beta,
                             const float* __restrict__ res_w, int layer) {
    __shared__ float sc[256], sh[256];
    int t = threadIdx.x;
    {
        float mean = bnsum[t] * (1.0f / Nn);
        float var  = fmaxf(bnsq[t] * (1.0f / Nn) - mean * mean, 0.f);
        float rstd = rsqrtf(var + 1e-5f);
        float s = gamma[t] * rstd;
        sc[t] = s; sh[t] = beta[t] - mean * s;
    }
    float m0 = res_w[0];
#pragma unroll
    for (int i = 1; i < Lnum; ++i) m0 = fmaxf(m0, res_w[i]);
    float se = 0.f, wl = 0.f;
#pragma unroll
    for (int i = 0; i < Lnum; ++i) {
        float e = __expf(res_w[i] - m0);
        se += e;
        if (i == layer) wl = e;
    }
    float wi = wl / se;
    __syncthreads();

    int idx = blockIdx.x * blockDim.x + t;
    int c8 = idx & 31;
    float scl[8], shl[8];
#pragma unroll
    for (int k = 0; k < 8; ++k) { scl[k] = sc[c8 * 8 + k]; shl[k] = sh[c8 * 8 + k]; }

    uint4 tv = ((const uint4*)T)[idx];
    uint4 xv = ((const uint4*)X)[idx];
    float tf[8], xf[8];
    unpack2(tv.x, tf[0], tf[1]); unpack2(tv.y, tf[2], tf[3]);
    unpack2(tv.z, tf[4], tf[5]); unpack2(tv.w, tf[6], tf[7]);
    unpack2(xv.x, xf[0], xf[1]); unpack2(xv.y, xf[2], xf[3]);
    unpack2(xv.z, xf[4], xf[5]); unpack2(xv.w, xf[6], xf[7]);

    float a[8];
#pragma unroll
    for (int k = 0; k < 8; ++k)
        a[k] = fmaxf(tf[k] * scl[k] + shl[k], 0.f) + 0.2f * xf[k];
    if (layer > 0) {
        uint4 hv = ((const uint4*)Hb)[idx];
        float hf[8];
        unpack2(hv.x, hf[0], hf[1]); unpack2(hv.y, hf[2], hf[3]);
        unpack2(hv.z, hf[4], hf[5]); unpack2(hv.w, hf[6], hf[7]);
#pragma unroll
        for (int k = 0; k < 8; ++k) a[k] += 0.7f * hf[k];
    }
    uint4 ho;
    ho.x = pack2(a[0], a[1]); ho.y = pack2(a[2], a[3]);
    ho.z = pack2(a[4], a[5]); ho.w = pack2(a[6], a[7]);
    ((uint4*)Hb)[idx] = ho;

    float m[8];
    if (layer == 0) {
#pragma unroll
        for (int k = 0; k < 8; ++k) m[k] = wi * a[k];
    } else {
        uint4 mv = ((const uint4*)M)[idx];
        float mf[8];
        unpack2(mv.x, mf[0], mf[1]); unpack2(mv.y, mf[2], mf[3]);
        unpack2(mv.z, mf[4], mf[5]); unpack2(mv.w, mf[6], mf[7]);
#pragma unroll
        for (int k = 0; k < 8; ++k) m[k] = mf[k] + wi * a[k];
    }
    uint4 mo;
    mo.x = pack2(m[0], m[1]); mo.y = pack2(m[2], m[3]);
    mo.z = pack2(m[4], m[5]); mo.w = pack2(m[6], m[7]);
    ((uint4*)M)[idx] = mo;
}

// ---------------------------------------------------------------------------
// Apply (H-array path): H_l = relu(T*s+b) + 0.2X (+0.7H_{l-1}).
// No M accumulator stream (mix deferred to head_mix). -102 MB/layer traffic.
// ---------------------------------------------------------------------------
__global__ void apply_h(const unsigned short* __restrict__ T,
                        const unsigned short* __restrict__ X,
                        const unsigned short* __restrict__ Hprev,
                        unsigned short* __restrict__ Hout,
                        const float* __restrict__ bnsum, const float* __restrict__ bnsq,
                        const float* __restrict__ gamma, const float* __restrict__ beta,
                        int layer) {
    __shared__ float sc[256], sh[256];
    int t = threadIdx.x;
    {
        float mean = bnsum[t] * (1.0f / Nn);
        float var  = fmaxf(bnsq[t] * (1.0f / Nn) - mean * mean, 0.f);
        float rstd = rsqrtf(var + 1e-5f);
        float s = gamma[t] * rstd;
        sc[t] = s; sh[t] = beta[t] - mean * s;
    }
    __syncthreads();

    int idx = blockIdx.x * blockDim.x + t;
    int c8 = idx & 31;
    float scl[8], shl[8];
#pragma unroll
    for (int k = 0; k < 8; ++k) { scl[k] = sc[c8 * 8 + k]; shl[k] = sh[c8 * 8 + k]; }

    uint4 tv = ((const uint4*)T)[idx];
    uint4 xv = ((const uint4*)X)[idx];
    float tf[8], xf[8];
    unpack2(tv.x, tf[0], tf[1]); unpack2(tv.y, tf[2], tf[3]);
    unpack2(tv.z, tf[4], tf[5]); unpack2(tv.w, tf[6], tf[7]);
    unpack2(xv.x, xf[0], xf[1]); unpack2(xv.y, xf[2], xf[3]);
    unpack2(xv.z, xf[4], xf[5]); unpack2(xv.w, xf[6], xf[7]);

    float a[8];
#pragma unroll
    for (int k = 0; k < 8; ++k)
        a[k] = fmaxf(tf[k] * scl[k] + shl[k], 0.f) + 0.2f * xf[k];
    if (layer > 0) {
        uint4 hv = ((const uint4*)Hprev)[idx];
        float hf[8];
        unpack2(hv.x, hf[0], hf[1]); unpack2(hv.y, hf[2], hf[3]);
        unpack2(hv.z, hf[4], hf[5]); unpack2(hv.w, hf[6], hf[7]);
#pragma unroll
        for (int k = 0; k < 8; ++k) a[k] += 0.7f * hf[k];
    }
    uint4 ho;
    ho.x = pack2(a[0], a[1]); ho.y = pack2(a[2], a[3]);
    ho.z = pack2(a[4], a[5]); ho.w = pack2(a[6], a[7]);
    ((uint4*)Hout)[idx] = ho;
}

// ---------------------------------------------------------------------------
// Head (fallback / M path): logits = M @ out_w + b, log_softmax.
// ---------------------------------------------------------------------------
__global__ __launch_bounds__(512) void head_mfma(const unsigned short* __restrict__ M,
                                                 const unsigned short* __restrict__ Whd,
                                                 const unsigned short* __restrict__ Wld,
                                                 const float* __restrict__ out_b,
                                                 float* __restrict__ out, int nrows) {
    __shared__ unsigned short At[128 * 40];
    const int t    = threadIdx.x;
    const int lane = t & 63, wid = t >> 6;
    const int ln   = lane & 15, quad = lane >> 4;
    const int r0   = blockIdx.x * 128;

    f32x4 acc[3];
#pragma unroll
    for (int ct = 0; ct < 3; ++ct) acc[ct] = (f32x4){0.f, 0.f, 0.f, 0.f};

    for (int k0 = 0; k0 < 256; k0 += 32) {
        __syncthreads();
        {
            int row = t >> 2, kq = t & 3;
            uint4 g = make_uint4(0u, 0u, 0u, 0u);
            if (r0 + row < nrows)
                g = *(const uint4*)&M[(size_t)(r0 + row) * 256 + k0 + kq * 8];
            *(uint4*)&At[row * 40 + kq * 8] = g;
        }
        __syncthreads();
        bf16x8 af = *(const bf16x8*)&At[(wid * 16 + ln) * 40 + quad * 8];
#pragma unroll
        for (int ct = 0; ct < 3; ++ct) {
            int c = ct * 16 + ln;
            bf16x8 bh = *(const bf16x8*)&Whd[c * 256 + k0 + quad * 8];
            bf16x8 bl = *(const bf16x8*)&Wld[c * 256 + k0 + quad * 8];
            acc[ct] = __builtin_amdgcn_mfma_f32_16x16x32_bf16(af, bh, acc[ct], 0, 0, 0);
            acc[ct] = __builtin_amdgcn_mfma_f32_16x16x32_bf16(af, bl, acc[ct], 0, 0, 0);
        }
    }

    int   cc[3]; float bias[3];
#pragma unroll
    for (int ct = 0; ct < 3; ++ct) {
        cc[ct] = ct * 16 + ln;
        bias[ct] = (cc[ct] < Ncls) ? out_b[cc[ct]] : 0.f;
    }
#pragma unroll
    for (int v = 0; v < 4; ++v) {
        int row = r0 + wid * 16 + quad * 4 + v;
        float val[3];
#pragma unroll
        for (int ct = 0; ct < 3; ++ct) val[ct] = acc[ct][v] + bias[ct];
        float mx = -1e30f;
#pragma unroll
        for (int ct = 0; ct < 3; ++ct) if (cc[ct] < Ncls) mx = fmaxf(mx, val[ct]);
        mx = fmaxf(mx, __shfl_xor(mx, 1)); mx = fmaxf(mx, __shfl_xor(mx, 2));
        mx = fmaxf(mx, __shfl_xor(mx, 4)); mx = fmaxf(mx, __shfl_xor(mx, 8));
        float s = 0.f;
#pragma unroll
        for (int ct = 0; ct < 3; ++ct) if (cc[ct] < Ncls) s += __expf(val[ct] - mx);
        s += __shfl_xor(s, 1); s += __shfl_xor(s, 2);
        s += __shfl_xor(s, 4); s += __shfl_xor(s, 8);
        float lse = mx + __logf(s);
        if (row < nrows) {
            out[(size_t)row * Ncls + cc[0]] = val[0] - lse;
            out[(size_t)row * Ncls + cc[1]] = val[1] - lse;
            if (ln < 8) out[(size_t)row * Ncls + cc[2]] = val[2] - lse;
        }
    }
}

// ---------------------------------------------------------------------------
// Head (H-array path): mix = sum_l softmax(res_w)[l] * H_l built in fp32
// during staging (single rounding), then logits + log_softmax.
// ---------------------------------------------------------------------------
__global__ __launch_bounds__(512) void head_mix(const unsigned short* __restrict__ H0,
                                                const unsigned short* __restrict__ Whd,
                                                const unsigned short* __restrict__ Wld,
                                                const float* __restrict__ out_b,
                                                const float* __restrict__ res_w,
                                                float* __restrict__ out, int nrows) {
    __shared__ unsigned short At[128 * 40];
    const int t    = threadIdx.x;
    const int lane = t & 63, wid = t >> 6;
    const int ln   = lane & 15, quad = lane >> 4;
    const int r0   = blockIdx.x * 128;

    float wmix[Lnum];
    {
        float m0 = res_w[0];
#pragma unroll
        for (int i = 1; i < Lnum; ++i) m0 = fmaxf(m0, res_w[i]);
        float se = 0.f;
#pragma unroll
        for (int i = 0; i < Lnum; ++i) { wmix[i] = __expf(res_w[i] - m0); se += wmix[i]; }
        float inv = 1.0f / se;
#pragma unroll
        for (int i = 0; i < Lnum; ++i) wmix[i] *= inv;
    }

    f32x4 acc[3];
#pragma unroll
    for (int ct = 0; ct < 3; ++ct) acc[ct] = (f32x4){0.f, 0.f, 0.f, 0.f};

    for (int k0 = 0; k0 < 256; k0 += 32) {
        __syncthreads();
        {
            int row = t >> 2, kq = t & 3;
            float m[8] = {0.f,0.f,0.f,0.f,0.f,0.f,0.f,0.f};
            if (r0 + row < nrows) {
                size_t base = (size_t)(r0 + row) * 256 + k0 + kq * 8;
#pragma unroll
                for (int l = 0; l < Lnum; ++l) {
                    uint4 g = *(const uint4*)&H0[(size_t)l * Nn * Hdim + base];
                    float f0, f1;
                    unpack2(g.x, f0, f1); m[0] += wmix[l] * f0; m[1] += wmix[l] * f1;
                    unpack2(g.y, f0, f1); m[2] += wmix[l] * f0; m[3] += wmix[l] * f1;
                    unpack2(g.z, f0, f1); m[4] += wmix[l] * f0; m[5] += wmix[l] * f1;
                    unpack2(g.w, f0, f1); m[6] += wmix[l] * f0; m[7] += wmix[l] * f1;
                }
            }
            uint4 o;
            o.x = pack2(m[0], m[1]); o.y = pack2(m[2], m[3]);
            o.z = pack2(m[4], m[5]); o.w = pack2(m[6], m[7]);
            *(uint4*)&At[row * 40 + kq * 8] = o;
        }
        __syncthreads();
        bf16x8 af = *(const bf16x8*)&At[(wid * 16 + ln) * 40 + quad * 8];
#pragma unroll
        for (int ct = 0; ct < 3; ++ct) {
            int c = ct * 16 + ln;
            bf16x8 bh = *(const bf16x8*)&Whd[c * 256 + k0 + quad * 8];
            bf16x8 bl = *(const bf16x8*)&Wld[c * 256 + k0 + quad * 8];
            acc[ct] = __builtin_amdgcn_mfma_f32_16x16x32_bf16(af, bh, acc[ct], 0, 0, 0);
            acc[ct] = __builtin_amdgcn_mfma_f32_16x16x32_bf16(af, bl, acc[ct], 0, 0, 0);
        }
    }

    int   cc[3]; float bias[3];
#pragma unroll
    for (int ct = 0; ct < 3; ++ct) {
        cc[ct] = ct * 16 + ln;
        bias[ct] = (cc[ct] < Ncls) ? out_b[cc[ct]] : 0.f;
    }
#pragma unroll
    for (int v = 0; v < 4; ++v) {
        int row = r0 + wid * 16 + quad * 4 + v;
        float val[3];
#pragma unroll
        for (int ct = 0; ct < 3; ++ct) val[ct] = acc[ct][v] + bias[ct];
        float mx = -1e30f;
#pragma unroll
        for (int ct = 0; ct < 3; ++ct) if (cc[ct] < Ncls) mx = fmaxf(mx, val[ct]);
        mx = fmaxf(mx, __shfl_xor(mx, 1)); mx = fmaxf(mx, __shfl_xor(mx, 2));
        mx = fmaxf(mx, __shfl_xor(mx, 4)); mx = fmaxf(mx, __shfl_xor(mx, 8));
        float s = 0.f;
#pragma unroll
        for (int ct = 0; ct < 3; ++ct) if (cc[ct] < Ncls) s += __expf(val[ct] - mx);
        s += __shfl_xor(s, 1); s += __shfl_xor(s, 2);
        s += __shfl_xor(s, 4); s += __shfl_xor(s, 8);
        float lse = mx + __logf(s);
        if (row < nrows) {
            out[(size_t)row * Ncls + cc[0]] = val[0] - lse;
            out[(size_t)row * Ncls + cc[1]] = val[1] - lse;
            if (ln < 8) out[(size_t)row * Ncls + cc[2]] = val[2] - lse;
        }
    }
}

// ---------------------------------------------------------------------------
extern "C" void kernel_launch(void* const* d_in, const int* in_sizes, int n_in,
                              void* d_out, int out_size, void* d_ws, size_t ws_size,
                              hipStream_t stream)
{
    const float* x      = (const float*)d_in[0];
    const int*   ei     = (const int*)d_in[1];
    const float* w_in   = (const float*)d_in[2];
    const float* b_in   = (const float*)d_in[3];
    const float* conv_w = (const float*)d_in[4];
    const float* conv_b = (const float*)d_in[5];
    const float* gamma  = (const float*)d_in[6];
    const float* beta   = (const float*)d_in[7];
    const float* out_w  = (const float*)d_in[8];
    const float* out_b  = (const float*)d_in[9];
    const float* res_w  = (const float*)d_in[10];
    float* out = (float*)d_out;
    char* ws = (char*)d_ws;

    // fixed prefix layout
    int*   cnt    = (int*)  (ws + 0);
    int*   cursor = (int*)  (ws + 400000);
    int*   offs   = (int*)  (ws + 800000);
    float* dinvp  = (float*)(ws + 1200016);
    int*   esrc   = (int*)  (ws + 1600016);
    float* ew     = (float*)(ws + 2800016);
    int*   iscan  = (int*)  (ws + 4002064);
    int*   btot   = (int*)  (ws + 4402064);
    int*   bpref  = (int*)  (ws + 4402576);
    unsigned short* Whi = (unsigned short*)(ws + 4403088);   // [L][256][256] bf16
    unsigned short* Fhi = (unsigned short*)(ws + 5975952);   // [256][128] bf16
    unsigned short* Whd = (unsigned short*)(ws + 6107024);   // [48][256] bf16
    unsigned short* Wld = (unsigned short*)(ws + 6131600);

    // per-layer BN stats bnA[L][512] alias the head of the dead iscan region
    float* bnA = (float*)(ws + 4002064);

    const int gblocks = (Nn + 127) / 128;   // 782
    const size_t NH = (size_t)Nn * Hdim;    // elems per activation buffer

    // --- H-array layout (preferred): X, T, H0..H5, Pstats ---
    const size_t HARR_P_OFS = 6156176 + 8 * NH * sizeof(unsigned short);
    const size_t P_BYTES = (size_t)gblocks * 512 * sizeof(float);
    const bool harr = (ws_size >= HARR_P_OFS + P_BYTES);

    unsigned short* X; unsigned short* T; unsigned short* Hb; unsigned short* M;
    unsigned short* Harr; unsigned short* xbf; float* Pst;

    if (harr) {
        X    = (unsigned short*)(ws + 6156176);
        T    = X + NH;
        Harr = T + NH;            // H0..H5 contiguous, stride NH
        Hb = nullptr; M = nullptr;
        xbf  = Harr + 5 * NH;     // alias H5: dead until layer-5 apply (fc runs first)
        Pst  = (float*)(ws + HARR_P_OFS);
    } else {
        // legacy layout: X, Hb, T, M
        X   = (unsigned short*)(ws + 6156176);
        Hb  = X + NH;
        T   = Hb + NH;
        M   = T + NH;
        Harr = nullptr;
        xbf = M;                  // alias: fc input, dead before M first written
        const size_t P_OFS = 6156176 + 4 * NH * sizeof(unsigned short);
        Pst = (ws_size >= P_OFS + P_BYTES) ? (float*)(ws + P_OFS) : nullptr;
    }

    hipMemsetAsync(cnt, 0, 800000, stream);  // cnt + cursor

    count_edges<<<(Ee + 255) / 256, 256, 0, stream>>>(ei, cnt);
    scan_block<<<SCAN_B, 1024, 0, stream>>>(cnt, iscan, btot);
    scan_tops<<<1, 128, 0, stream>>>(btot, bpref);
    scan_final<<<SCAN_B, 1024, 0, stream>>>(cnt, iscan, bpref, offs, dinvp);
    fill_csr<<<(Ee + 255) / 256, 256, 0, stream>>>(ei, offs, cursor, dinvp, esrc, ew);

    // iscan dead from here; zero the per-layer bn stats region once
    hipMemsetAsync(bnA, 0, Lnum * 512 * sizeof(float), stream);

    prep_weights<<<1712, 256, 0, stream>>>(conv_w, w_in, out_w,
                                           Whi, Fhi, Whd, Wld);
    cvt_bf16<<<(Nn * FIN / 8 + 255) / 256, 256, 0, stream>>>(x, xbf, Nn * FIN / 8);

    gemm_fc<<<gblocks, 512, 0, stream>>>(xbf, X, Fhi, b_in, Nn);

    for (int i = 0; i < Lnum; ++i) {
        float* bnsumL = bnA + (size_t)i * 512;
        float* bnsqL  = bnsumL + 256;
        const unsigned short* Hin =
            (i == 0) ? X : (harr ? Harr + (size_t)(i - 1) * NH : Hb);
        gemm_agg<<<gblocks, 512, 0, stream>>>(Hin, T,
                                              Whi + (size_t)i * Hdim * Hdim,
                                              conv_b + (size_t)i * Hdim,
                                              offs, esrc, ew, dinvp,
                                              bnsumL, bnsqL, Pst);
        if (Pst)
            bn_reduce<<<64, 256, 0, stream>>>(Pst, bnsumL, bnsqL, gblocks);
        if (harr) {
            apply_h<<<(Nn * 32) / 256, 256, 0, stream>>>(
                T, X, (i == 0) ? X : Harr + (size_t)(i - 1) * NH,
                Harr + (size_t)i * NH,
                bnsumL, bnsqL,
                gamma + (size_t)i * Hdim, beta + (size_t)i * Hdim, i);
        } else {
            apply_kernel<<<(Nn * 32) / 256, 256, 0, stream>>>(
                T, X, Hb, M, bnsumL, bnsqL,
                gamma + (size_t)i * Hdim, beta + (size_t)i * Hdim,
                res_w, i);
        }
    }

    if (harr)
        head_mix<<<gblocks, 512, 0, stream>>>(Harr, Whd, Wld, out_b, res_w, out, Nn);
    else
        head_mfma<<<gblocks, 512, 0, stream>>>(M, Whd, Wld, out_b, out, Nn);
}